// Round 9
// baseline (694.207 us; speedup 1.0000x reference)
//
#include <hip/hip_runtime.h>
#include <math.h>

#define L 4
#define BATCH 4
#define N 2048
#define D 512
#define H 8
#define DH 64
#define MLPD 2048
#define M_ROWS (BATCH * N)  // 8192
#define VTP 2064            // V^T row pitch (shorts): 2048 + 16 to break 4KB aliasing

using v8s = __attribute__((ext_vector_type(8))) short;   // 8 x bf16
using v4f = __attribute__((ext_vector_type(4))) float;

__device__ inline short f2bf(float f) {
  union { float f; unsigned u; } v; v.f = f;
  unsigned r = v.u + 0x7FFFu + ((v.u >> 16) & 1u);   // RNE
  return (short)(r >> 16);
}
__device__ inline unsigned pack2bf_t(float a, float b) {   // truncating pack (P only)
  union { float f; unsigned u; } x, y; x.f = a; y.f = b;
  return (x.u >> 16) | (y.u & 0xFFFF0000u);
}

#define MFMA(a, b, c) __builtin_amdgcn_mfma_f32_16x16x32_bf16(a, b, c, 0, 0, 0)

// async 16B/lane global->LDS (dest = wave-uniform base + lane*16; SOURCE is per-lane)
__device__ __forceinline__ void gload_lds16(const void* g, void* l) {
  __builtin_amdgcn_global_load_lds((const __attribute__((address_space(1))) void*)g,
                                   (__attribute__((address_space(3))) void*)l, 16, 0, 0);
}

// compiler-motion fences / raw barrier / counted vmem wait
#define FENCE asm volatile("" ::: "memory")
#define BAR  do { FENCE; __builtin_amdgcn_s_barrier(); FENCE; } while (0)
#define VMW(n) asm volatile("s_waitcnt vmcnt(" #n ")" ::: "memory")

// ------------------------------------------------- fp32 [R][C] -> bf16 [C][R], per layer z
// qcols > 0: output rows (= source cols) < qcols get scaled by 0.125 (exact bf16
// exponent shift) — folds the attention 1/sqrt(DH) into the Q weight columns.
__launch_bounds__(256)
__global__ void transpose_w_kernel(const float* __restrict__ src, short* __restrict__ dst,
                                   int R, int C, int qcols) {
  __shared__ float tile[32][33];
  const size_t base = (size_t)blockIdx.z * R * C;
  const int c0 = blockIdx.x * 32, r0 = blockIdx.y * 32;
  const int tx = threadIdx.x & 31, ty = threadIdx.x >> 5;   // 32 x 8
  #pragma unroll
  for (int i = ty; i < 32; i += 8)
    tile[i][tx] = src[base + (size_t)(r0 + i) * C + c0 + tx];
  __syncthreads();
  #pragma unroll
  for (int i = ty; i < 32; i += 8) {
    float val = tile[tx][i];
    if (c0 + i < qcols) val *= 0.125f;
    dst[base + (size_t)(c0 + i) * R + r0 + tx] = f2bf(val);
  }
}

// ---------------------------------------------------------------- LayerNorm (wave per row)
__launch_bounds__(256)
__global__ void ln_kernel(const float* __restrict__ x, const float* __restrict__ w,
                          const float* __restrict__ b, short* __restrict__ out) {
  const int row = blockIdx.x * 4 + (threadIdx.x >> 6);
  const int lane = threadIdx.x & 63;
  const float* xr = x + (size_t)row * D;
  float4 a0 = *(const float4*)(xr + lane * 8);
  float4 a1 = *(const float4*)(xr + lane * 8 + 4);
  float v[8] = {a0.x, a0.y, a0.z, a0.w, a1.x, a1.y, a1.z, a1.w};
  float s = 0.f;
  #pragma unroll
  for (int j = 0; j < 8; ++j) s += v[j];
  #pragma unroll
  for (int m = 1; m < 64; m <<= 1) s += __shfl_xor(s, m, 64);
  const float mean = s * (1.0f / D);
  float q = 0.f;
  #pragma unroll
  for (int j = 0; j < 8; ++j) { float d = v[j] - mean; q += d * d; }
  #pragma unroll
  for (int m = 1; m < 64; m <<= 1) q += __shfl_xor(q, m, 64);
  const float rstd = rsqrtf(q * (1.0f / D) + 1e-5f);
  float4 w0 = *(const float4*)(w + lane * 8);
  float4 w1 = *(const float4*)(w + lane * 8 + 4);
  float4 b0 = *(const float4*)(b + lane * 8);
  float4 b1 = *(const float4*)(b + lane * 8 + 4);
  float wv[8] = {w0.x, w0.y, w0.z, w0.w, w1.x, w1.y, w1.z, w1.w};
  float bv[8] = {b0.x, b0.y, b0.z, b0.w, b1.x, b1.y, b1.z, b1.w};
  v8s r;
  #pragma unroll
  for (int j = 0; j < 8; ++j) r[j] = f2bf((v[j] - mean) * rstd * wv[j] + bv[j]);
  *(v8s*)(out + (size_t)row * D + lane * 8) = r;
}

// ---------------------------------------------------------------- 256x256 8-phase GEMM
// (R1 notes) + R4 VMW(6) + tail source-clamped stages.
// MODE 0: bf16 out   1: bf16 gelu(out+bias)
// MODE 3: qkv fused epilogue — V column-blocks (n0>=1024) written transposed +
//   kappa^{-1}-permuted into Vt ONLY; Q/K blocks take the normal bf16 path.
template <int MODE, int NT>   // K = NT*64
__launch_bounds__(512, 2)
__global__ void gemm256_kernel(const short* __restrict__ A, const short* __restrict__ Bt,
                               const float* __restrict__ bias, void* __restrict__ Out,
                               short* __restrict__ Vt, int M, int Nc) {
  constexpr int K = NT * 64;
  __shared__ __align__(16) short Ah[4][128 * 64];
  __shared__ __align__(16) short Bh[4][128 * 64];
  const int tid = threadIdx.x, lane = tid & 63, w = tid >> 6;
  const int wr = w >> 2, wc = w & 3;          // 2M x 4N wave grid
  const int r16 = lane & 15, g = lane >> 4;

  const int nxb = Nc >> 8;
  const int nyb = M >> 8;
  const int bid = (int)blockIdx.x;
  const int xcd = bid & 7, ii = bid >> 3;
  const int byi = xcd * (nyb >> 3) + ii / nxb;
  const int bxi = ii % nxb;
  const int m0 = byi << 8, n0 = bxi << 8;

  const int srow = lane >> 3;                  // row within 8-row gload strip
  const int ssw = ((lane & 7) ^ srow) * 8;     // preswizzled short offset in 128B row

  const short* Abase = A + (size_t)(m0 + srow) * K + ssw;
  const short* Bbase = Bt + (size_t)(n0 + srow) * K + ssw;

  auto STAGE_A = [&](int j) {                  // half-index j: K-tile j>>1, half j&1
    const int jc = (j > 2 * NT - 1) ? (2 * NT - 1) : j;   // tail: dummy (slot never re-read)
    const int slot = j & 3, k0 = (jc >> 1) * 64, r0 = (jc & 1) * 128;
    #pragma unroll
    for (int i = 0; i < 2; ++i) {
      const int rr = i * 64 + w * 8;
      gload_lds16(Abase + (size_t)(r0 + rr) * K + k0, (char*)&Ah[slot][0] + rr * 128);
    }
  };
  auto STAGE_B = [&](int j) {
    const int jc = (j > 2 * NT - 1) ? (2 * NT - 1) : j;
    const int slot = j & 3, k0 = (jc >> 1) * 64, c0 = (jc & 1) * 128;
    #pragma unroll
    for (int i = 0; i < 2; ++i) {
      const int rr = i * 64 + w * 8;
      gload_lds16(Bbase + (size_t)(c0 + rr) * K + k0, (char*)&Bh[slot][0] + rr * 128);
    }
  };

  const int arow = wr * 64 + r16;              // row within A slot (+ mf*16)
  const int brow = wc * 32 + r16;              // col within B slot (+ nf*16)
  const int swz7 = r16 & 7;

  v8s ar[4][2], br0[2][2], br1[2][2];
  auto LDA = [&](int slot) {
    const char* base = (const char*)&Ah[slot][0];
    #pragma unroll
    for (int mf = 0; mf < 4; ++mf)
      #pragma unroll
      for (int kh = 0; kh < 2; ++kh)
        ar[mf][kh] = *(const v8s*)(base + (arow + mf * 16) * 128 + (((kh * 4 + g) ^ swz7) * 16));
  };
  auto LDB0 = [&](int slot) {
    const char* base = (const char*)&Bh[slot][0];
    #pragma unroll
    for (int nf = 0; nf < 2; ++nf)
      #pragma unroll
      for (int kh = 0; kh < 2; ++kh)
        br0[nf][kh] = *(const v8s*)(base + (brow + nf * 16) * 128 + (((kh * 4 + g) ^ swz7) * 16));
  };
  auto LDB1 = [&](int slot) {
    const char* base = (const char*)&Bh[slot][0];
    #pragma unroll
    for (int nf = 0; nf < 2; ++nf)
      #pragma unroll
      for (int kh = 0; kh < 2; ++kh)
        br1[nf][kh] = *(const v8s*)(base + (brow + nf * 16) * 128 + (((kh * 4 + g) ^ swz7) * 16));
  };

  v4f acc[2][2][4][2] = {};   // [qm][qn][mf][nf]

#define MMA_Q(QM, QN, BR)                                                      \
  do {                                                                         \
    __builtin_amdgcn_s_setprio(1);                                             \
    _Pragma("unroll")                                                          \
    for (int kh = 0; kh < 2; ++kh)                                             \
      _Pragma("unroll")                                                        \
      for (int mf = 0; mf < 4; ++mf)                                           \
        _Pragma("unroll")                                                      \
        for (int nf = 0; nf < 2; ++nf)                                         \
          acc[QM][QN][mf][nf] = MFMA(ar[mf][kh], BR[nf][kh], acc[QM][QN][mf][nf]); \
    __builtin_amdgcn_s_setprio(0);                                             \
  } while (0)

  STAGE_A(0); STAGE_B(0); STAGE_B(1); STAGE_A(1); STAGE_A(2); STAGE_B(2); STAGE_B(3);
  VMW(6);
  BAR;

  auto KTILE = [&](int T, int sa) {
    // ---- P0: quadrant (0,0)
    LDA(sa); LDB0(sa);
    STAGE_A(2 * T + 3);
    BAR;
    MMA_Q(0, 0, br0);
    BAR;
    // ---- P1: quadrant (0,1)
    LDB1(sa + 1);
    BAR;
    MMA_Q(0, 1, br1);
    BAR;
    // ---- P2: quadrant (1,1)
    LDA(sa + 1);
    STAGE_A(2 * T + 4); STAGE_B(2 * T + 4);
    BAR;
    MMA_Q(1, 1, br1);
    BAR;
    // ---- P3: quadrant (1,0)
    STAGE_B(2 * T + 5);
    BAR;
    MMA_Q(1, 0, br0);
    VMW(6);   // retires exactly T+1's 4 half-tiles; 3 newest stay in flight
    BAR;
  };

  #pragma unroll
  for (int t2 = 0; t2 < NT / 2; ++t2) {
    KTILE(2 * t2, 0);
    KTILE(2 * t2 + 1, 2);
  }
#undef MMA_Q

  // ---- epilogue
  if constexpr (MODE == 3) {
    if (n0 >= 1024) {
      // V column-block: write kappa^{-1}-permuted V^T into Vt only.
      const int bb = m0 >> 11;                       // batch (block spans one batch)
      const int cperm = 16 * (g >> 1) + 8 * (g & 1); // g-dependent column bits
      #pragma unroll
      for (int qm = 0; qm < 2; ++qm)
        #pragma unroll
        for (int mf = 0; mf < 4; ++mf) {
          const int key0 = m0 + qm * 128 + wr * 64 + mf * 16;   // 16-aligned group base
          const int ng = (key0 & 2047) & ~63;                   // 64-group within seq
          // key bits: k5k4 = mf, k3k2 = g, k1k0 = r  ->  c = 32*(mf>>1)+16*(g>>1)+8*(g&1)+4*(mf&1)
          const int ccol = 32 * (mf >> 1) + cperm + 4 * (mf & 1);
          #pragma unroll
          for (int qn = 0; qn < 2; ++qn)
            #pragma unroll
            for (int nf = 0; nf < 2; ++nf) {
              const int col = n0 + qn * 128 + wc * 32 + nf * 16 + r16;
              const int dhg = col - 1024;
              const int bh = bb * 8 + (dhg >> 6);
              short* dst = Vt + (size_t)(bh * 64 + (dhg & 63)) * VTP + ng + ccol;
              uint2 st;
              st.x = (unsigned)(unsigned short)f2bf(acc[qm][qn][mf][nf][0]) |
                     ((unsigned)(unsigned short)f2bf(acc[qm][qn][mf][nf][1]) << 16);
              st.y = (unsigned)(unsigned short)f2bf(acc[qm][qn][mf][nf][2]) |
                     ((unsigned)(unsigned short)f2bf(acc[qm][qn][mf][nf][3]) << 16);
              *(uint2*)dst = st;
            }
        }
      return;
    }
  }
  #pragma unroll
  for (int qm = 0; qm < 2; ++qm)
    #pragma unroll
    for (int mf = 0; mf < 4; ++mf) {
      const int row = m0 + qm * 128 + wr * 64 + mf * 16 + g * 4;
      #pragma unroll
      for (int qn = 0; qn < 2; ++qn)
        #pragma unroll
        for (int nf = 0; nf < 2; ++nf) {
          const int col = n0 + qn * 128 + wc * 32 + nf * 16 + r16;
          float bv = 0.0f;
          if constexpr (MODE == 1) bv = bias[col];
          #pragma unroll
          for (int r = 0; r < 4; ++r) {
            float val = acc[qm][qn][mf][nf][r] + bv;
            if constexpr (MODE == 1) {
              const float z = val * 0.70710678118f;
              const float az = fabsf(z);
              const float t = 1.0f / (1.0f + 0.3275911f * az);
              const float p =
                  0.254829592f +
                  t * (-0.284496736f + t * (1.421413741f + t * (-1.453152027f + t * 1.061405429f)));
              float er = 1.0f - p * t * __expf(-az * az);
              er = (z < 0.0f) ? -er : er;
              val = 0.5f * val * (1.0f + er);
            }
            ((short*)Out)[(size_t)(row + r) * Nc + col] = f2bf(val);
          }
        }
    }
}

// ---------------------------------------------------------------- GEMM: C = A[M,K] * Bt[Nc,K]^T
// (R4 version — 2-deep + __syncthreads; R6's counted-vmcnt variant measured worse.)
template <int MODE, int BN>
__launch_bounds__(256)
__global__ void gemm128_kernel(const short* __restrict__ A, const short* __restrict__ Bt,
                               const float* __restrict__ bias, const float* __restrict__ Xres,
                               void* __restrict__ Out, int M, int Nc, int K) {
  constexpr int MR = (BN == 128) ? 4 : 2;
  __shared__ __align__(16) short As[2][128 * 64];   // [buf][row][64 shorts], chunk-swizzled
  __shared__ __align__(16) short Bs[2][BN * 64];
  const int tid = threadIdx.x;
  const int lane = tid & 63;
  const int w = tid >> 6;
  const int wr = (BN == 128) ? (w >> 1) : w;
  const int wc = (BN == 128) ? (w & 1) : 0;
  const int r16 = lane & 15, g = lane >> 4;

  const int nxb = Nc / BN;
  const int nyb = M >> 7;
  const int bid = (int)blockIdx.x;
  const int xcd = bid & 7;
  const int ii = bid >> 3;
  const int byi = xcd * (nyb >> 3) + ii / nxb;
  const int bxi = ii % nxb;
  const int m0 = byi * 128, n0 = bxi * BN;

  const int srow = lane >> 3;                  // row within 8-row gload
  const int ssw = ((lane & 7) ^ srow) * 8;     // preswizzled short offset within 128B row

  auto STAGE = [&](int buf, int k0) {
    #pragma unroll
    for (int j = 0; j < 4; ++j) {              // A: 128 rows, 4 instr/wave
      const int row = w * 32 + j * 8;
      gload_lds16(A + (size_t)(m0 + row + srow) * K + k0 + ssw,
                  (char*)&As[buf][0] + row * 128);
    }
    #pragma unroll
    for (int j = 0; j < BN / 32; ++j) {        // B: BN rows, BN/32 instr/wave
      const int row = w * (BN / 4) + j * 8;
      gload_lds16(Bt + (size_t)(n0 + row + srow) * K + k0 + ssw,
                  (char*)&Bs[buf][0] + row * 128);
    }
  };

  v4f acc[MR][4] = {};

  STAGE(0, 0);
  __syncthreads();   // prefetch 0 landed
  int cur = 0;
  for (int k0 = 0; k0 < K; k0 += 64) {
    if (k0 + 64 < K) STAGE(cur ^ 1, k0 + 64);   // overlap with compute below
    v8s af[MR][2], bf[4][2];
    #pragma unroll
    for (int m = 0; m < MR; ++m) {
      const int row = wr * (MR * 16) + m * 16 + r16;
      #pragma unroll
      for (int kh = 0; kh < 2; ++kh)
        af[m][kh] = *(const v8s*)((const char*)&As[cur][0] + row * 128 +
                                  (((kh * 4 + g) ^ (row & 7)) * 16));
    }
    #pragma unroll
    for (int n = 0; n < 4; ++n) {
      const int row = wc * 64 + n * 16 + r16;
      #pragma unroll
      for (int kh = 0; kh < 2; ++kh)
        bf[n][kh] = *(const v8s*)((const char*)&Bs[cur][0] + row * 128 +
                                  (((kh * 4 + g) ^ (row & 7)) * 16));
    }
    #pragma unroll
    for (int kh = 0; kh < 2; ++kh)
      #pragma unroll
      for (int m = 0; m < MR; ++m)
        #pragma unroll
        for (int n = 0; n < 4; ++n)
          acc[m][n] = MFMA(af[m][kh], bf[n][kh], acc[m][n]);
    __syncthreads();   // drains vmcnt (next buf ready) + fences LDS reuse
    cur ^= 1;
  }

  #pragma unroll
  for (int m = 0; m < MR; ++m) {
    const int row = m0 + wr * (MR * 16) + m * 16 + g * 4;
    #pragma unroll
    for (int n = 0; n < 4; ++n) {
      const int col = n0 + wc * 64 + n * 16 + r16;
      const float bv = bias ? bias[col] : 0.0f;
      #pragma unroll
      for (int r = 0; r < 4; ++r) {
        const size_t idx = (size_t)(row + r) * Nc + col;
        float val = acc[m][n][r] + bv;
        if constexpr (MODE == 0) {
          ((short*)Out)[idx] = f2bf(val);
        } else if constexpr (MODE == 1) {
          const float z = val * 0.70710678118f;
          const float az = fabsf(z);
          const float t = 1.0f / (1.0f + 0.3275911f * az);
          const float p =
              0.254829592f +
              t * (-0.284496736f + t * (1.421413741f + t * (-1.453152027f + t * 1.061405429f)));
          float er = 1.0f - p * t * __expf(-az * az);
          er = (z < 0.0f) ? -er : er;
          val = 0.5f * val * (1.0f + er);
          ((short*)Out)[idx] = f2bf(val);
        } else {
          ((float*)Out)[idx] = val + Xres[idx];
        }
      }
    }
  }
}

// ---------------------------------------------------------------- causal flash attention v16
// v13 structure with V read DIRECTLY from L2-resident Vt (kappa-permuted layout):
// removes per-tile-per-wave 8 ds_read_b128 (half the LDS pipe), STAGE_V, and the
// Vs buffers (LDS 40->24KB). Grid 1024 / 4 waves / 16 q-rows per wave and the
// proven conflict-free K pattern are UNCHANGED (R2+R7 lesson: never shrink TLP).
// vf loads issue at iteration top, before STAGE_K(t+2): the compiler's vf-wait
// before PV is vmcnt(2), which also retires K(t+1) -> every wave's K-landed
// point precedes its next barrier (v13 invariant preserved).
__launch_bounds__(256)
__global__ void attn_kernel(const short* __restrict__ qkv, const short* __restrict__ Vt,
                            short* __restrict__ o) {
  __shared__ __align__(16) short Ks[3][64 * 64];   // key-major, XOR-swizzled
  const int lin = (int)blockIdx.x;
  const int bh = ((lin >> 3) & 3) * 8 + (lin & 7);
  const int xl2 = 31 - (lin >> 5);
  const int b = bh >> 3, h = bh & 7;
  const int q0 = xl2 * 64;
  const int tid = threadIdx.x, lane = tid & 63, w = tid >> 6;
  const int r16 = lane & 15, g = lane >> 4;
  const int qw = q0 + w * 16;

  v8s qf0, qf1;
  {
    const size_t qbase = ((size_t)(b * N + qw + r16)) * 1536 + h * 64;
    qf0 = *(const v8s*)(qkv + qbase + g * 8);        // Q[:, 0:32] (prescaled 1/8)
    qf1 = *(const v8s*)(qkv + qbase + 32 + g * 8);   // Q[:, 32:64]
  }

  const short* vtb = Vt + (size_t)bh * 64 * VTP;
  const short* vrow = vtb + (size_t)r16 * VTP;      // lane's V^T row base (+ a*16*VTP)

  const int srow = lane >> 3;                    // row within staging instruction
  const int ssw = ((lane & 7) ^ srow) * 8;       // XOR-preswizzled short offset in row

  v4f oacc[4] = {};
  float lsum = 0.f;                               // running sum for q = qw + r16
  const int tdiag = xl2;

  auto STAGE_K = [&](int t) {
    t = (t > tdiag) ? tdiag : t;                 // tail clamp (same-value dup)
    const int k0 = t * 64, buf = t % 3;
    #pragma unroll
    for (int j = 0; j < 2; ++j) {
      const int row = w * 16 + j * 8;
      gload_lds16(qkv + ((size_t)(b * N + k0 + row + srow)) * 1536 + 512 + h * 64 + ssw,
                  (char*)&Ks[buf][0] + row * 128);
    }
  };

  // prologue: K(0), K(1) staged (4 loads outstanding)
  STAGE_K(0); STAGE_K(1);

  for (int t = 0; t <= tdiag; ++t) {
    VMW(2);            // t=0: retires K(0); t>0: no-op (K(t) retired by vf(t-1) wait)
    BAR;               // all waves: tile-t K landed; K slot t-1 free for overwrite

    // --- V fragments direct from L1/L2 (Vt is XCD-L2-resident, kappa-permuted) ---
    const int k0 = t * 64;
    v8s vf[4][2];
    #pragma unroll
    for (int a = 0; a < 4; ++a)
      #pragma unroll
      for (int c = 0; c < 2; ++c)
        vf[a][c] = *(const v8s*)(vrow + (size_t)(a * 16) * VTP + k0 + c * 32 + g * 8);

    STAGE_K(t + 2);    // issued AFTER vf loads: vf-wait => vmcnt(2) keeps these flying

    const char* kb = (const char*)&Ks[t % 3][0];

    // --- S^T = K * Q^T : lane holds S[key = k0+16kt+4g+r][q = qw+r16] ---
    __builtin_amdgcn_s_setprio(1);
    v4f s[4];
    #pragma unroll
    for (int kt = 0; kt < 4; ++kt) {
      const int krow = (kt * 16 + r16) * 128;
      v8s kfa = *(const v8s*)(kb + krow + ((g ^ (r16 & 7)) * 16));
      v8s kfb = *(const v8s*)(kb + krow + (((4 + g) ^ (r16 & 7)) * 16));
      v4f ss = {};
      ss = MFMA(kfa, qf0, ss);
      ss = MFMA(kfb, qf1, ss);
      s[kt] = ss;
    }
    __builtin_amdgcn_s_setprio(0);

    // --- softmax numerator in registers (scale pre-folded into Q) ---
    const bool needmask = (t == tdiag);
    const int qrow = qw + r16;
    const int kbase = t * 64 + 4 * g;
    unsigned pw_[8];
    #pragma unroll
    for (int kt = 0; kt < 4; ++kt) {
      float e[4];
      #pragma unroll
      for (int r = 0; r < 4; ++r) {
        float v = s[kt][r];
        if (needmask && (kbase + kt * 16 + r > qrow)) v = -3e38f;
        e[r] = __expf(v);
      }
      lsum += (e[0] + e[1]) + (e[2] + e[3]);
      pw_[kt * 2 + 0] = pack2bf_t(e[0], e[1]);
      pw_[kt * 2 + 1] = pack2bf_t(e[2], e[3]);
    }
    union PU { unsigned u[4]; v8s s8; };
    PU pa0, pa1;
    pa0.u[0] = pw_[0]; pa0.u[1] = pw_[1]; pa0.u[2] = pw_[2]; pa0.u[3] = pw_[3];
    pa1.u[0] = pw_[4]; pa1.u[1] = pw_[5]; pa1.u[2] = pw_[6]; pa1.u[3] = pw_[7];

    // --- O += P * V (A = lane-local P, B = kappa-permuted V^T fragments) ---
    __builtin_amdgcn_s_setprio(1);
    #pragma unroll
    for (int dt = 0; dt < 4; ++dt) oacc[dt] = MFMA(pa0.s8, vf[dt][0], oacc[dt]);
    #pragma unroll
    for (int dt = 0; dt < 4; ++dt) oacc[dt] = MFMA(pa1.s8, vf[dt][1], oacc[dt]);
    __builtin_amdgcn_s_setprio(0);
  }

  // reduce the 4 g-replicas of each q-row, then redistribute to the O layout
  lsum += __shfl_xor(lsum, 16, 64);
  lsum += __shfl_xor(lsum, 32, 64);
  const float linv = 1.0f / lsum;
  float ldiv[4];
  #pragma unroll
  for (int r = 0; r < 4; ++r) ldiv[r] = __shfl(linv, g * 4 + r, 64);

  #pragma unroll
  for (int dt = 0; dt < 4; ++dt)
    #pragma unroll
    for (int r = 0; r < 4; ++r) {
      const float val = oacc[dt][r] * ldiv[r];
      o[((size_t)(b * N + qw + g * 4 + r)) * 512 + h * 64 + dt * 16 + r16] = f2bf(val);
    }
}

// ----------------------------------------------------------------------------
extern "C" void kernel_launch(void* const* d_in, const int* in_sizes, int n_in,
                              void* d_out, int out_size, void* d_ws, size_t ws_size,
                              hipStream_t stream) {
  const float* x_in  = (const float*)d_in[0];
  // d_in[1] = mask (strict causal — baked into attn_kernel)
  const float* ln1_w = (const float*)d_in[2];
  const float* ln1_b = (const float*)d_in[3];
  const float* w_qkv = (const float*)d_in[4];
  const float* w_out = (const float*)d_in[5];
  const float* b_out = (const float*)d_in[6];
  const float* ln2_w = (const float*)d_in[7];
  const float* ln2_b = (const float*)d_in[8];
  const float* w1    = (const float*)d_in[9];
  const float* b1    = (const float*)d_in[10];
  const float* w2    = (const float*)d_in[11];
  const float* b2    = (const float*)d_in[12];

  char* ws = (char*)d_ws;
  size_t off = 0;
  auto alloc = [&](size_t bytes) { char* p = ws + off; off += (bytes + 255) & ~(size_t)255; return p; };
  short* wqkvT = (short*)alloc((size_t)L * 1536 * 512 * 2);
  short* woutT = (short*)alloc((size_t)L * 512 * 512 * 2);
  short* w1T   = (short*)alloc((size_t)L * 512 * 2048 * 2);
  short* w2T   = (short*)alloc((size_t)L * 2048 * 512 * 2);
  short* hln   = (short*)alloc((size_t)M_ROWS * 512 * 2);
  short* big   = (short*)alloc((size_t)M_ROWS * 2048 * 2);  // qkv (1536 cols) & ff (2048 cols) share
  short* oatt  = (short*)alloc((size_t)M_ROWS * 512 * 2);
  short* Vtg   = (short*)alloc((size_t)BATCH * H * 64 * VTP * 2);
  short* qkv = big;
  short* ff  = big;

  float* x = (float*)d_out;   // fp32 residual stream lives in d_out
  // No upfront copy: layer 0 reads x_in directly (ln1 + out-proj residual);
  // out-proj MODE 2 writes ALL of x before anything reads it.

  transpose_w_kernel<<<dim3(1536 / 32, 512 / 32, L), 256, 0, stream>>>(w_qkv, wqkvT, 512, 1536, 512);
  transpose_w_kernel<<<dim3(512 / 32, 512 / 32, L), 256, 0, stream>>>(w_out, woutT, 512, 512, 0);
  transpose_w_kernel<<<dim3(2048 / 32, 512 / 32, L), 256, 0, stream>>>(w1, w1T, 512, 2048, 0);
  transpose_w_kernel<<<dim3(512 / 32, 2048 / 32, L), 256, 0, stream>>>(w2, w2T, 2048, 512, 0);

  for (int l = 0; l < L; ++l) {
    const float* xl = (l == 0) ? x_in : x;   // residual state entering this layer
    // --- attention block ---
    ln_kernel<<<M_ROWS / 4, 256, 0, stream>>>(xl, ln1_w + l * 512, ln1_b + l * 512, hln);
    gemm256_kernel<3, 8><<<dim3((1536 / 256) * (M_ROWS / 256)), 512, 0, stream>>>(
        hln, wqkvT + (size_t)l * 1536 * 512, nullptr, qkv, Vtg, M_ROWS, 1536);
    attn_kernel<<<dim3(1024), 256, 0, stream>>>(qkv, Vtg, oatt);
    gemm128_kernel<2, 64><<<dim3((512 / 64) * (M_ROWS / 128)), 256, 0, stream>>>(
        oatt, woutT + (size_t)l * 512 * 512, b_out + l * 512, xl, x, M_ROWS, 512, 512);
    // --- MLP block ---
    ln_kernel<<<M_ROWS / 4, 256, 0, stream>>>(x, ln2_w + l * 512, ln2_b + l * 512, hln);
    gemm256_kernel<1, 8><<<dim3((2048 / 256) * (M_ROWS / 256)), 512, 0, stream>>>(
        hln, w1T + (size_t)l * 512 * 2048, b1 + l * 2048, ff, nullptr, M_ROWS, 2048);
    gemm128_kernel<2, 64><<<dim3((512 / 64) * (M_ROWS / 128)), 256, 0, stream>>>(
        ff, w2T + (size_t)l * 2048 * 512, b2 + l * 512, x, x, M_ROWS, 512, 2048);
  }
}

// Round 10
// 593.254 us; speedup vs baseline: 1.1702x; 1.1702x over previous
//
#include <hip/hip_runtime.h>
#include <math.h>

#define L 4
#define BATCH 4
#define N 2048
#define D 512
#define H 8
#define DH 64
#define MLPD 2048
#define M_ROWS (BATCH * N)  // 8192
#define VTP 2064            // V^T row pitch (shorts): 2048 + 16 to break 4KB aliasing

using v8s = __attribute__((ext_vector_type(8))) short;   // 8 x bf16
using v4f = __attribute__((ext_vector_type(4))) float;

__device__ inline short f2bf(float f) {
  union { float f; unsigned u; } v; v.f = f;
  unsigned r = v.u + 0x7FFFu + ((v.u >> 16) & 1u);   // RNE
  return (short)(r >> 16);
}
__device__ inline unsigned pack2bf_t(float a, float b) {   // truncating pack (P only)
  union { float f; unsigned u; } x, y; x.f = a; y.f = b;
  return (x.u >> 16) | (y.u & 0xFFFF0000u);
}

#define MFMA(a, b, c) __builtin_amdgcn_mfma_f32_16x16x32_bf16(a, b, c, 0, 0, 0)

// async 16B/lane global->LDS (dest = wave-uniform base + lane*16; SOURCE is per-lane)
__device__ __forceinline__ void gload_lds16(const void* g, void* l) {
  __builtin_amdgcn_global_load_lds((const __attribute__((address_space(1))) void*)g,
                                   (__attribute__((address_space(3))) void*)l, 16, 0, 0);
}

// compiler-motion fences / raw barrier / counted vmem wait
#define FENCE asm volatile("" ::: "memory")
#define BAR  do { FENCE; __builtin_amdgcn_s_barrier(); FENCE; } while (0)
#define VMW(n) asm volatile("s_waitcnt vmcnt(" #n ")" ::: "memory")

// ------------------------------------------------- fp32 [R][C] -> bf16 [C][R], per layer z
// qcols > 0: output rows (= source cols) < qcols get scaled by 0.125 (exact bf16
// exponent shift) — folds the attention 1/sqrt(DH) into the Q weight columns.
__launch_bounds__(256)
__global__ void transpose_w_kernel(const float* __restrict__ src, short* __restrict__ dst,
                                   int R, int C, int qcols) {
  __shared__ float tile[32][33];
  const size_t base = (size_t)blockIdx.z * R * C;
  const int c0 = blockIdx.x * 32, r0 = blockIdx.y * 32;
  const int tx = threadIdx.x & 31, ty = threadIdx.x >> 5;   // 32 x 8
  #pragma unroll
  for (int i = ty; i < 32; i += 8)
    tile[i][tx] = src[base + (size_t)(r0 + i) * C + c0 + tx];
  __syncthreads();
  #pragma unroll
  for (int i = ty; i < 32; i += 8) {
    float val = tile[tx][i];
    if (c0 + i < qcols) val *= 0.125f;
    dst[base + (size_t)(c0 + i) * R + r0 + tx] = f2bf(val);
  }
}

// ---------------------------------------------------------------- LayerNorm (wave per row)
__launch_bounds__(256)
__global__ void ln_kernel(const float* __restrict__ x, const float* __restrict__ w,
                          const float* __restrict__ b, short* __restrict__ out) {
  const int row = blockIdx.x * 4 + (threadIdx.x >> 6);
  const int lane = threadIdx.x & 63;
  const float* xr = x + (size_t)row * D;
  float4 a0 = *(const float4*)(xr + lane * 8);
  float4 a1 = *(const float4*)(xr + lane * 8 + 4);
  float v[8] = {a0.x, a0.y, a0.z, a0.w, a1.x, a1.y, a1.z, a1.w};
  float s = 0.f;
  #pragma unroll
  for (int j = 0; j < 8; ++j) s += v[j];
  #pragma unroll
  for (int m = 1; m < 64; m <<= 1) s += __shfl_xor(s, m, 64);
  const float mean = s * (1.0f / D);
  float q = 0.f;
  #pragma unroll
  for (int j = 0; j < 8; ++j) { float d = v[j] - mean; q += d * d; }
  #pragma unroll
  for (int m = 1; m < 64; m <<= 1) q += __shfl_xor(q, m, 64);
  const float rstd = rsqrtf(q * (1.0f / D) + 1e-5f);
  float4 w0 = *(const float4*)(w + lane * 8);
  float4 w1 = *(const float4*)(w + lane * 8 + 4);
  float4 b0 = *(const float4*)(b + lane * 8);
  float4 b1 = *(const float4*)(b + lane * 8 + 4);
  float wv[8] = {w0.x, w0.y, w0.z, w0.w, w1.x, w1.y, w1.z, w1.w};
  float bv[8] = {b0.x, b0.y, b0.z, b0.w, b1.x, b1.y, b1.z, b1.w};
  v8s r;
  #pragma unroll
  for (int j = 0; j < 8; ++j) r[j] = f2bf((v[j] - mean) * rstd * wv[j] + bv[j]);
  *(v8s*)(out + (size_t)row * D + lane * 8) = r;
}

// ---------------------------------------------------------------- 256x256 8-phase GEMM
// (R1 notes) + R4 VMW(6) + tail source-clamped stages.
// MODE 0: bf16 out   1: bf16 gelu(out+bias)
// MODE 3: qkv fused epilogue — V column-blocks (n0>=1024) written transposed +
//   kappa^{-1}-permuted into Vt ONLY; Q/K blocks take the normal bf16 path.
template <int MODE, int NT>   // K = NT*64
__launch_bounds__(512, 2)
__global__ void gemm256_kernel(const short* __restrict__ A, const short* __restrict__ Bt,
                               const float* __restrict__ bias, void* __restrict__ Out,
                               short* __restrict__ Vt, int M, int Nc) {
  constexpr int K = NT * 64;
  __shared__ __align__(16) short Ah[4][128 * 64];
  __shared__ __align__(16) short Bh[4][128 * 64];
  const int tid = threadIdx.x, lane = tid & 63, w = tid >> 6;
  const int wr = w >> 2, wc = w & 3;          // 2M x 4N wave grid
  const int r16 = lane & 15, g = lane >> 4;

  const int nxb = Nc >> 8;
  const int nyb = M >> 8;
  const int bid = (int)blockIdx.x;
  const int xcd = bid & 7, ii = bid >> 3;
  const int byi = xcd * (nyb >> 3) + ii / nxb;
  const int bxi = ii % nxb;
  const int m0 = byi << 8, n0 = bxi << 8;

  const int srow = lane >> 3;                  // row within 8-row gload strip
  const int ssw = ((lane & 7) ^ srow) * 8;     // preswizzled short offset in 128B row

  const short* Abase = A + (size_t)(m0 + srow) * K + ssw;
  const short* Bbase = Bt + (size_t)(n0 + srow) * K + ssw;

  auto STAGE_A = [&](int j) {                  // half-index j: K-tile j>>1, half j&1
    const int jc = (j > 2 * NT - 1) ? (2 * NT - 1) : j;   // tail: dummy (slot never re-read)
    const int slot = j & 3, k0 = (jc >> 1) * 64, r0 = (jc & 1) * 128;
    #pragma unroll
    for (int i = 0; i < 2; ++i) {
      const int rr = i * 64 + w * 8;
      gload_lds16(Abase + (size_t)(r0 + rr) * K + k0, (char*)&Ah[slot][0] + rr * 128);
    }
  };
  auto STAGE_B = [&](int j) {
    const int jc = (j > 2 * NT - 1) ? (2 * NT - 1) : j;
    const int slot = j & 3, k0 = (jc >> 1) * 64, c0 = (jc & 1) * 128;
    #pragma unroll
    for (int i = 0; i < 2; ++i) {
      const int rr = i * 64 + w * 8;
      gload_lds16(Bbase + (size_t)(c0 + rr) * K + k0, (char*)&Bh[slot][0] + rr * 128);
    }
  };

  const int arow = wr * 64 + r16;              // row within A slot (+ mf*16)
  const int brow = wc * 32 + r16;              // col within B slot (+ nf*16)
  const int swz7 = r16 & 7;

  v8s ar[4][2], br0[2][2], br1[2][2];
  auto LDA = [&](int slot) {
    const char* base = (const char*)&Ah[slot][0];
    #pragma unroll
    for (int mf = 0; mf < 4; ++mf)
      #pragma unroll
      for (int kh = 0; kh < 2; ++kh)
        ar[mf][kh] = *(const v8s*)(base + (arow + mf * 16) * 128 + (((kh * 4 + g) ^ swz7) * 16));
  };
  auto LDB0 = [&](int slot) {
    const char* base = (const char*)&Bh[slot][0];
    #pragma unroll
    for (int nf = 0; nf < 2; ++nf)
      #pragma unroll
      for (int kh = 0; kh < 2; ++kh)
        br0[nf][kh] = *(const v8s*)(base + (brow + nf * 16) * 128 + (((kh * 4 + g) ^ swz7) * 16));
  };
  auto LDB1 = [&](int slot) {
    const char* base = (const char*)&Bh[slot][0];
    #pragma unroll
    for (int nf = 0; nf < 2; ++nf)
      #pragma unroll
      for (int kh = 0; kh < 2; ++kh)
        br1[nf][kh] = *(const v8s*)(base + (brow + nf * 16) * 128 + (((kh * 4 + g) ^ swz7) * 16));
  };

  v4f acc[2][2][4][2] = {};   // [qm][qn][mf][nf]

#define MMA_Q(QM, QN, BR)                                                      \
  do {                                                                         \
    __builtin_amdgcn_s_setprio(1);                                             \
    _Pragma("unroll")                                                          \
    for (int kh = 0; kh < 2; ++kh)                                             \
      _Pragma("unroll")                                                        \
      for (int mf = 0; mf < 4; ++mf)                                           \
        _Pragma("unroll")                                                      \
        for (int nf = 0; nf < 2; ++nf)                                         \
          acc[QM][QN][mf][nf] = MFMA(ar[mf][kh], BR[nf][kh], acc[QM][QN][mf][nf]); \
    __builtin_amdgcn_s_setprio(0);                                             \
  } while (0)

  STAGE_A(0); STAGE_B(0); STAGE_B(1); STAGE_A(1); STAGE_A(2); STAGE_B(2); STAGE_B(3);
  VMW(6);
  BAR;

  auto KTILE = [&](int T, int sa) {
    // ---- P0: quadrant (0,0)
    LDA(sa); LDB0(sa);
    STAGE_A(2 * T + 3);
    BAR;
    MMA_Q(0, 0, br0);
    BAR;
    // ---- P1: quadrant (0,1)
    LDB1(sa + 1);
    BAR;
    MMA_Q(0, 1, br1);
    BAR;
    // ---- P2: quadrant (1,1)
    LDA(sa + 1);
    STAGE_A(2 * T + 4); STAGE_B(2 * T + 4);
    BAR;
    MMA_Q(1, 1, br1);
    BAR;
    // ---- P3: quadrant (1,0)
    STAGE_B(2 * T + 5);
    BAR;
    MMA_Q(1, 0, br0);
    VMW(6);   // retires exactly T+1's 4 half-tiles; 3 newest stay in flight
    BAR;
  };

  #pragma unroll
  for (int t2 = 0; t2 < NT / 2; ++t2) {
    KTILE(2 * t2, 0);
    KTILE(2 * t2 + 1, 2);
  }
#undef MMA_Q

  // ---- epilogue
  if constexpr (MODE == 3) {
    if (n0 >= 1024) {
      // V column-block: write kappa^{-1}-permuted V^T into Vt only.
      const int bb = m0 >> 11;                       // batch (block spans one batch)
      const int cperm = 16 * (g >> 1) + 8 * (g & 1); // g-dependent column bits
      #pragma unroll
      for (int qm = 0; qm < 2; ++qm)
        #pragma unroll
        for (int mf = 0; mf < 4; ++mf) {
          const int key0 = m0 + qm * 128 + wr * 64 + mf * 16;   // 16-aligned group base
          const int ng = (key0 & 2047) & ~63;                   // 64-group within seq
          // key bits: k5k4 = mf, k3k2 = g, k1k0 = r  ->  c = 32*(mf>>1)+16*(g>>1)+8*(g&1)+4*(mf&1)
          const int ccol = 32 * (mf >> 1) + cperm + 4 * (mf & 1);
          #pragma unroll
          for (int qn = 0; qn < 2; ++qn)
            #pragma unroll
            for (int nf = 0; nf < 2; ++nf) {
              const int col = n0 + qn * 128 + wc * 32 + nf * 16 + r16;
              const int dhg = col - 1024;
              const int bh = bb * 8 + (dhg >> 6);
              short* dst = Vt + (size_t)(bh * 64 + (dhg & 63)) * VTP + ng + ccol;
              uint2 st;
              st.x = (unsigned)(unsigned short)f2bf(acc[qm][qn][mf][nf][0]) |
                     ((unsigned)(unsigned short)f2bf(acc[qm][qn][mf][nf][1]) << 16);
              st.y = (unsigned)(unsigned short)f2bf(acc[qm][qn][mf][nf][2]) |
                     ((unsigned)(unsigned short)f2bf(acc[qm][qn][mf][nf][3]) << 16);
              *(uint2*)dst = st;
            }
        }
      return;
    }
  }
  #pragma unroll
  for (int qm = 0; qm < 2; ++qm)
    #pragma unroll
    for (int mf = 0; mf < 4; ++mf) {
      const int row = m0 + qm * 128 + wr * 64 + mf * 16 + g * 4;
      #pragma unroll
      for (int qn = 0; qn < 2; ++qn)
        #pragma unroll
        for (int nf = 0; nf < 2; ++nf) {
          const int col = n0 + qn * 128 + wc * 32 + nf * 16 + r16;
          float bv = 0.0f;
          if constexpr (MODE == 1) bv = bias[col];
          #pragma unroll
          for (int r = 0; r < 4; ++r) {
            float val = acc[qm][qn][mf][nf][r] + bv;
            if constexpr (MODE == 1) {
              const float z = val * 0.70710678118f;
              const float az = fabsf(z);
              const float t = 1.0f / (1.0f + 0.3275911f * az);
              const float p =
                  0.254829592f +
                  t * (-0.284496736f + t * (1.421413741f + t * (-1.453152027f + t * 1.061405429f)));
              float er = 1.0f - p * t * __expf(-az * az);
              er = (z < 0.0f) ? -er : er;
              val = 0.5f * val * (1.0f + er);
            }
            ((short*)Out)[(size_t)(row + r) * Nc + col] = f2bf(val);
          }
        }
    }
}

// ---------------------------------------------------------------- GEMM: C = A[M,K] * Bt[Nc,K]^T
// (R4 version — 2-deep + __syncthreads; R6's counted-vmcnt variant measured worse.)
template <int MODE, int BN>
__launch_bounds__(256)
__global__ void gemm128_kernel(const short* __restrict__ A, const short* __restrict__ Bt,
                               const float* __restrict__ bias, const float* __restrict__ Xres,
                               void* __restrict__ Out, int M, int Nc, int K) {
  constexpr int MR = (BN == 128) ? 4 : 2;
  __shared__ __align__(16) short As[2][128 * 64];   // [buf][row][64 shorts], chunk-swizzled
  __shared__ __align__(16) short Bs[2][BN * 64];
  const int tid = threadIdx.x;
  const int lane = tid & 63;
  const int w = tid >> 6;
  const int wr = (BN == 128) ? (w >> 1) : w;
  const int wc = (BN == 128) ? (w & 1) : 0;
  const int r16 = lane & 15, g = lane >> 4;

  const int nxb = Nc / BN;
  const int nyb = M >> 7;
  const int bid = (int)blockIdx.x;
  const int xcd = bid & 7;
  const int ii = bid >> 3;
  const int byi = xcd * (nyb >> 3) + ii / nxb;
  const int bxi = ii % nxb;
  const int m0 = byi * 128, n0 = bxi * BN;

  const int srow = lane >> 3;                  // row within 8-row gload
  const int ssw = ((lane & 7) ^ srow) * 8;     // preswizzled short offset within 128B row

  auto STAGE = [&](int buf, int k0) {
    #pragma unroll
    for (int j = 0; j < 4; ++j) {              // A: 128 rows, 4 instr/wave
      const int row = w * 32 + j * 8;
      gload_lds16(A + (size_t)(m0 + row + srow) * K + k0 + ssw,
                  (char*)&As[buf][0] + row * 128);
    }
    #pragma unroll
    for (int j = 0; j < BN / 32; ++j) {        // B: BN rows, BN/32 instr/wave
      const int row = w * (BN / 4) + j * 8;
      gload_lds16(Bt + (size_t)(n0 + row + srow) * K + k0 + ssw,
                  (char*)&Bs[buf][0] + row * 128);
    }
  };

  v4f acc[MR][4] = {};

  STAGE(0, 0);
  __syncthreads();   // prefetch 0 landed
  int cur = 0;
  for (int k0 = 0; k0 < K; k0 += 64) {
    if (k0 + 64 < K) STAGE(cur ^ 1, k0 + 64);   // overlap with compute below
    v8s af[MR][2], bf[4][2];
    #pragma unroll
    for (int m = 0; m < MR; ++m) {
      const int row = wr * (MR * 16) + m * 16 + r16;
      #pragma unroll
      for (int kh = 0; kh < 2; ++kh)
        af[m][kh] = *(const v8s*)((const char*)&As[cur][0] + row * 128 +
                                  (((kh * 4 + g) ^ (row & 7)) * 16));
    }
    #pragma unroll
    for (int n = 0; n < 4; ++n) {
      const int row = wc * 64 + n * 16 + r16;
      #pragma unroll
      for (int kh = 0; kh < 2; ++kh)
        bf[n][kh] = *(const v8s*)((const char*)&Bs[cur][0] + row * 128 +
                                  (((kh * 4 + g) ^ (row & 7)) * 16));
    }
    #pragma unroll
    for (int kh = 0; kh < 2; ++kh)
      #pragma unroll
      for (int m = 0; m < MR; ++m)
        #pragma unroll
        for (int n = 0; n < 4; ++n)
          acc[m][n] = MFMA(af[m][kh], bf[n][kh], acc[m][n]);
    __syncthreads();   // drains vmcnt (next buf ready) + fences LDS reuse
    cur ^= 1;
  }

  #pragma unroll
  for (int m = 0; m < MR; ++m) {
    const int row = m0 + wr * (MR * 16) + m * 16 + g * 4;
    #pragma unroll
    for (int n = 0; n < 4; ++n) {
      const int col = n0 + wc * 64 + n * 16 + r16;
      const float bv = bias ? bias[col] : 0.0f;
      #pragma unroll
      for (int r = 0; r < 4; ++r) {
        const size_t idx = (size_t)(row + r) * Nc + col;
        float val = acc[m][n][r] + bv;
        if constexpr (MODE == 0) {
          ((short*)Out)[idx] = f2bf(val);
        } else if constexpr (MODE == 1) {
          const float z = val * 0.70710678118f;
          const float az = fabsf(z);
          const float t = 1.0f / (1.0f + 0.3275911f * az);
          const float p =
              0.254829592f +
              t * (-0.284496736f + t * (1.421413741f + t * (-1.453152027f + t * 1.061405429f)));
          float er = 1.0f - p * t * __expf(-az * az);
          er = (z < 0.0f) ? -er : er;
          val = 0.5f * val * (1.0f + er);
          ((short*)Out)[idx] = f2bf(val);
        } else {
          ((float*)Out)[idx] = val + Xres[idx];
        }
      }
    }
  }
}

// ---------------------------------------------------------------- causal flash attention v13
// (R3/R4 verified version — best measured. Ks 3-deep + Vs 2-deep LDS, counted
// vmcnt, Q prescaled by 1/8 in wqkvT, reciprocal-multiply epilogue.
// R5 T15 deferred-PV, R7 dual-Q, and R8 V-direct-from-L2 all regressed:
// this kernel's 4-blocks/CU TLP is the load-bearing latency-hiding mechanism.)
__launch_bounds__(256)
__global__ void attn_kernel(const short* __restrict__ qkv, const short* __restrict__ Vt,
                            short* __restrict__ o) {
  __shared__ __align__(16) short Ks[3][64 * 64];   // key-major, XOR-swizzled
  __shared__ __align__(16) short Vs[2][64 * 64];   // dh-major,  XOR-swizzled
  const int lin = (int)blockIdx.x;
  const int bh = ((lin >> 3) & 3) * 8 + (lin & 7);
  const int xl2 = 31 - (lin >> 5);
  const int b = bh >> 3, h = bh & 7;
  const int q0 = xl2 * 64;
  const int tid = threadIdx.x, lane = tid & 63, w = tid >> 6;
  const int r16 = lane & 15, g = lane >> 4;
  const int qw = q0 + w * 16;

  v8s qf0, qf1;
  {
    const size_t qbase = ((size_t)(b * N + qw + r16)) * 1536 + h * 64;
    qf0 = *(const v8s*)(qkv + qbase + g * 8);        // Q[:, 0:32] (prescaled 1/8)
    qf1 = *(const v8s*)(qkv + qbase + 32 + g * 8);   // Q[:, 32:64]
  }

  const short* vtb = Vt + (size_t)bh * 64 * VTP;

  const int srow = lane >> 3;                    // row within instruction
  const int ssw = ((lane & 7) ^ srow) * 8;       // XOR-preswizzled short offset in row

  v4f oacc[4] = {};
  float lsum = 0.f;                               // running sum for q = qw + r16
  const int tdiag = xl2;

  auto STAGE_K = [&](int t) {
    t = (t > tdiag) ? tdiag : t;                 // tail clamp (same-value dup)
    const int k0 = t * 64, buf = t % 3;
    #pragma unroll
    for (int j = 0; j < 2; ++j) {
      const int row = w * 16 + j * 8;
      gload_lds16(qkv + ((size_t)(b * N + k0 + row + srow)) * 1536 + 512 + h * 64 + ssw,
                  (char*)&Ks[buf][0] + row * 128);
    }
  };
  auto STAGE_V = [&](int t) {
    t = (t > tdiag) ? tdiag : t;
    const int k0 = t * 64, buf = t & 1;
    #pragma unroll
    for (int j = 0; j < 2; ++j) {
      const int row = w * 16 + j * 8;
      gload_lds16(vtb + (size_t)(row + srow) * VTP + k0 + ssw,
                  (char*)&Vs[buf][0] + row * 128);
    }
  };

  // prologue: K(0), V(0), K(1) -> queue holds 6 loads, VMW(2) in tile 0 retires K0,V0
  STAGE_K(0); STAGE_V(0); STAGE_K(1);

  for (int t = 0; t <= tdiag; ++t) {
    VMW(2);
    BAR;               // all waves: tile-t K/V landed; prev buffers free for overwrite
    STAGE_V(t + 1);
    STAGE_K(t + 2);

    const char* kb = (const char*)&Ks[t % 3][0];
    const char* vb = (const char*)&Vs[t & 1][0];

    v8s vf[4][2];
    #pragma unroll
    for (int a = 0; a < 4; ++a)
      #pragma unroll
      for (int c = 0; c < 2; ++c)
        vf[a][c] = *(const v8s*)(vb + (a * 16 + r16) * 128 + (((c * 4 + g) ^ (r16 & 7)) * 16));

    // --- S^T = K * Q^T : lane holds S[key = k0+16kt+4g+r][q = qw+r16] ---
    __builtin_amdgcn_s_setprio(1);
    v4f s[4];
    #pragma unroll
    for (int kt = 0; kt < 4; ++kt) {
      const int krow = (kt * 16 + r16) * 128;
      v8s kfa = *(const v8s*)(kb + krow + ((g ^ (r16 & 7)) * 16));
      v8s kfb = *(const v8s*)(kb + krow + (((4 + g) ^ (r16 & 7)) * 16));
      v4f ss = {};
      ss = MFMA(kfa, qf0, ss);
      ss = MFMA(kfb, qf1, ss);
      s[kt] = ss;
    }
    __builtin_amdgcn_s_setprio(0);

    // --- softmax numerator in registers (scale pre-folded into Q) ---
    const bool needmask = (t == tdiag);
    const int qrow = qw + r16;
    const int kbase = t * 64 + 4 * g;
    unsigned pw_[8];
    #pragma unroll
    for (int kt = 0; kt < 4; ++kt) {
      float e[4];
      #pragma unroll
      for (int r = 0; r < 4; ++r) {
        float v = s[kt][r];
        if (needmask && (kbase + kt * 16 + r > qrow)) v = -3e38f;
        e[r] = __expf(v);
      }
      lsum += (e[0] + e[1]) + (e[2] + e[3]);
      pw_[kt * 2 + 0] = pack2bf_t(e[0], e[1]);
      pw_[kt * 2 + 1] = pack2bf_t(e[2], e[3]);
    }
    union PU { unsigned u[4]; v8s s8; };
    PU pa0, pa1;
    pa0.u[0] = pw_[0]; pa0.u[1] = pw_[1]; pa0.u[2] = pw_[2]; pa0.u[3] = pw_[3];
    pa1.u[0] = pw_[4]; pa1.u[1] = pw_[5]; pa1.u[2] = pw_[6]; pa1.u[3] = pw_[7];

    // --- O += P * V (A = lane-local P, B = kappa-permuted V^T fragments) ---
    __builtin_amdgcn_s_setprio(1);
    #pragma unroll
    for (int dt = 0; dt < 4; ++dt) oacc[dt] = MFMA(pa0.s8, vf[dt][0], oacc[dt]);
    #pragma unroll
    for (int dt = 0; dt < 4; ++dt) oacc[dt] = MFMA(pa1.s8, vf[dt][1], oacc[dt]);
    __builtin_amdgcn_s_setprio(0);
  }

  // reduce the 4 g-replicas of each q-row, then redistribute to the O layout
  lsum += __shfl_xor(lsum, 16, 64);
  lsum += __shfl_xor(lsum, 32, 64);
  const float linv = 1.0f / lsum;
  float ldiv[4];
  #pragma unroll
  for (int r = 0; r < 4; ++r) ldiv[r] = __shfl(linv, g * 4 + r, 64);

  #pragma unroll
  for (int dt = 0; dt < 4; ++dt)
    #pragma unroll
    for (int r = 0; r < 4; ++r) {
      const float val = oacc[dt][r] * ldiv[r];
      o[((size_t)(b * N + qw + g * 4 + r)) * 512 + h * 64 + dt * 16 + r16] = f2bf(val);
    }
}

// ----------------------------------------------------------------------------
extern "C" void kernel_launch(void* const* d_in, const int* in_sizes, int n_in,
                              void* d_out, int out_size, void* d_ws, size_t ws_size,
                              hipStream_t stream) {
  const float* x_in  = (const float*)d_in[0];
  // d_in[1] = mask (strict causal — baked into attn_kernel)
  const float* ln1_w = (const float*)d_in[2];
  const float* ln1_b = (const float*)d_in[3];
  const float* w_qkv = (const float*)d_in[4];
  const float* w_out = (const float*)d_in[5];
  const float* b_out = (const float*)d_in[6];
  const float* ln2_w = (const float*)d_in[7];
  const float* ln2_b = (const float*)d_in[8];
  const float* w1    = (const float*)d_in[9];
  const float* b1    = (const float*)d_in[10];
  const float* w2    = (const float*)d_in[11];
  const float* b2    = (const float*)d_in[12];

  char* ws = (char*)d_ws;
  size_t off = 0;
  auto alloc = [&](size_t bytes) { char* p = ws + off; off += (bytes + 255) & ~(size_t)255; return p; };
  short* wqkvT = (short*)alloc((size_t)L * 1536 * 512 * 2);
  short* woutT = (short*)alloc((size_t)L * 512 * 512 * 2);
  short* w1T   = (short*)alloc((size_t)L * 512 * 2048 * 2);
  short* w2T   = (short*)alloc((size_t)L * 2048 * 512 * 2);
  short* hln   = (short*)alloc((size_t)M_ROWS * 512 * 2);
  short* big   = (short*)alloc((size_t)M_ROWS * 2048 * 2);  // qkv (1536 cols) & ff (2048 cols) share
  short* oatt  = (short*)alloc((size_t)M_ROWS * 512 * 2);
  short* Vtg   = (short*)alloc((size_t)BATCH * H * 64 * VTP * 2);
  short* qkv = big;
  short* ff  = big;

  float* x = (float*)d_out;   // fp32 residual stream lives in d_out
  // No upfront copy: layer 0 reads x_in directly (ln1 + out-proj residual);
  // out-proj MODE 2 writes ALL of x before anything reads it.

  transpose_w_kernel<<<dim3(1536 / 32, 512 / 32, L), 256, 0, stream>>>(w_qkv, wqkvT, 512, 1536, 512);
  transpose_w_kernel<<<dim3(512 / 32, 512 / 32, L), 256, 0, stream>>>(w_out, woutT, 512, 512, 0);
  transpose_w_kernel<<<dim3(2048 / 32, 512 / 32, L), 256, 0, stream>>>(w1, w1T, 512, 2048, 0);
  transpose_w_kernel<<<dim3(512 / 32, 2048 / 32, L), 256, 0, stream>>>(w2, w2T, 2048, 512, 0);

  for (int l = 0; l < L; ++l) {
    const float* xl = (l == 0) ? x_in : x;   // residual state entering this layer
    // --- attention block ---
    ln_kernel<<<M_ROWS / 4, 256, 0, stream>>>(xl, ln1_w + l * 512, ln1_b + l * 512, hln);
    gemm256_kernel<3, 8><<<dim3((1536 / 256) * (M_ROWS / 256)), 512, 0, stream>>>(
        hln, wqkvT + (size_t)l * 1536 * 512, nullptr, qkv, Vtg, M_ROWS, 1536);
    attn_kernel<<<dim3(1024), 256, 0, stream>>>(qkv, Vtg, oatt);
    gemm128_kernel<2, 64><<<dim3((512 / 64) * (M_ROWS / 128)), 256, 0, stream>>>(
        oatt, woutT + (size_t)l * 512 * 512, b_out + l * 512, xl, x, M_ROWS, 512, 512);
    // --- MLP block ---
    ln_kernel<<<M_ROWS / 4, 256, 0, stream>>>(x, ln2_w + l * 512, ln2_b + l * 512, hln);
    gemm256_kernel<1, 8><<<dim3((2048 / 256) * (M_ROWS / 256)), 512, 0, stream>>>(
        hln, w1T + (size_t)l * 512 * 2048, b1 + l * 2048, ff, nullptr, M_ROWS, 2048);
    gemm128_kernel<2, 64><<<dim3((512 / 64) * (M_ROWS / 128)), 256, 0, stream>>>(
        ff, w2T + (size_t)l * 2048 * 512, b2 + l * 512, x, x, M_ROWS, 512, 2048);
  }
}

// Round 11
// 591.988 us; speedup vs baseline: 1.1727x; 1.0021x over previous
//
#include <hip/hip_runtime.h>
#include <math.h>

#define L 4
#define BATCH 4
#define N 2048
#define D 512
#define H 8
#define DH 64
#define MLPD 2048
#define M_ROWS (BATCH * N)  // 8192
#define VTP 2064            // V^T row pitch (shorts): 2048 + 16 to break 4KB aliasing

using v8s = __attribute__((ext_vector_type(8))) short;   // 8 x bf16
using v4f = __attribute__((ext_vector_type(4))) float;

__device__ inline short f2bf(float f) {
  union { float f; unsigned u; } v; v.f = f;
  unsigned r = v.u + 0x7FFFu + ((v.u >> 16) & 1u);   // RNE
  return (short)(r >> 16);
}
__device__ inline unsigned pack2bf_t(float a, float b) {   // truncating pack (P only)
  union { float f; unsigned u; } x, y; x.f = a; y.f = b;
  return (x.u >> 16) | (y.u & 0xFFFF0000u);
}

#define MFMA(a, b, c) __builtin_amdgcn_mfma_f32_16x16x32_bf16(a, b, c, 0, 0, 0)

// async 16B/lane global->LDS (dest = wave-uniform base + lane*16; SOURCE is per-lane)
__device__ __forceinline__ void gload_lds16(const void* g, void* l) {
  __builtin_amdgcn_global_load_lds((const __attribute__((address_space(1))) void*)g,
                                   (__attribute__((address_space(3))) void*)l, 16, 0, 0);
}

// compiler-motion fences / raw barrier / counted vmem wait
#define FENCE asm volatile("" ::: "memory")
#define BAR  do { FENCE; __builtin_amdgcn_s_barrier(); FENCE; } while (0)
#define VMW(n) asm volatile("s_waitcnt vmcnt(" #n ")" ::: "memory")

// ------------------------------------------------- fp32 [R][C] -> bf16 [C][R], per layer z
// qcols > 0: output rows (= source cols) < qcols get scaled by 0.125 (exact bf16
// exponent shift) — folds the attention 1/sqrt(DH) into the Q weight columns.
__launch_bounds__(256)
__global__ void transpose_w_kernel(const float* __restrict__ src, short* __restrict__ dst,
                                   int R, int C, int qcols) {
  __shared__ float tile[32][33];
  const size_t base = (size_t)blockIdx.z * R * C;
  const int c0 = blockIdx.x * 32, r0 = blockIdx.y * 32;
  const int tx = threadIdx.x & 31, ty = threadIdx.x >> 5;   // 32 x 8
  #pragma unroll
  for (int i = ty; i < 32; i += 8)
    tile[i][tx] = src[base + (size_t)(r0 + i) * C + c0 + tx];
  __syncthreads();
  #pragma unroll
  for (int i = ty; i < 32; i += 8) {
    float val = tile[tx][i];
    if (c0 + i < qcols) val *= 0.125f;
    dst[base + (size_t)(c0 + i) * R + r0 + tx] = f2bf(val);
  }
}

// ---------------------------------------------------------------- LayerNorm (wave per row)
__launch_bounds__(256)
__global__ void ln_kernel(const float* __restrict__ x, const float* __restrict__ w,
                          const float* __restrict__ b, short* __restrict__ out) {
  const int row = blockIdx.x * 4 + (threadIdx.x >> 6);
  const int lane = threadIdx.x & 63;
  const float* xr = x + (size_t)row * D;
  float4 a0 = *(const float4*)(xr + lane * 8);
  float4 a1 = *(const float4*)(xr + lane * 8 + 4);
  float v[8] = {a0.x, a0.y, a0.z, a0.w, a1.x, a1.y, a1.z, a1.w};
  float s = 0.f;
  #pragma unroll
  for (int j = 0; j < 8; ++j) s += v[j];
  #pragma unroll
  for (int m = 1; m < 64; m <<= 1) s += __shfl_xor(s, m, 64);
  const float mean = s * (1.0f / D);
  float q = 0.f;
  #pragma unroll
  for (int j = 0; j < 8; ++j) { float d = v[j] - mean; q += d * d; }
  #pragma unroll
  for (int m = 1; m < 64; m <<= 1) q += __shfl_xor(q, m, 64);
  const float rstd = rsqrtf(q * (1.0f / D) + 1e-5f);
  float4 w0 = *(const float4*)(w + lane * 8);
  float4 w1 = *(const float4*)(w + lane * 8 + 4);
  float4 b0 = *(const float4*)(b + lane * 8);
  float4 b1 = *(const float4*)(b + lane * 8 + 4);
  float wv[8] = {w0.x, w0.y, w0.z, w0.w, w1.x, w1.y, w1.z, w1.w};
  float bv[8] = {b0.x, b0.y, b0.z, b0.w, b1.x, b1.y, b1.z, b1.w};
  v8s r;
  #pragma unroll
  for (int j = 0; j < 8; ++j) r[j] = f2bf((v[j] - mean) * rstd * wv[j] + bv[j]);
  *(v8s*)(out + (size_t)row * D + lane * 8) = r;
}

// ---------------------------------------------------------------- 256x256 8-phase GEMM
// (R1 notes) + R4 VMW(6) + tail source-clamped stages.
// MODE 0: bf16 out   1: bf16 gelu(out+bias)
// MODE 3: qkv fused epilogue — V column-blocks (n0>=1024) written transposed +
//   kappa^{-1}-permuted into Vt ONLY; Q/K blocks take the normal bf16 path.
template <int MODE, int NT>   // K = NT*64
__launch_bounds__(512, 2)
__global__ void gemm256_kernel(const short* __restrict__ A, const short* __restrict__ Bt,
                               const float* __restrict__ bias, void* __restrict__ Out,
                               short* __restrict__ Vt, int M, int Nc) {
  constexpr int K = NT * 64;
  __shared__ __align__(16) short Ah[4][128 * 64];
  __shared__ __align__(16) short Bh[4][128 * 64];
  const int tid = threadIdx.x, lane = tid & 63, w = tid >> 6;
  const int wr = w >> 2, wc = w & 3;          // 2M x 4N wave grid
  const int r16 = lane & 15, g = lane >> 4;

  const int nxb = Nc >> 8;
  const int nyb = M >> 8;
  const int bid = (int)blockIdx.x;
  const int xcd = bid & 7, ii = bid >> 3;
  const int byi = xcd * (nyb >> 3) + ii / nxb;
  const int bxi = ii % nxb;
  const int m0 = byi << 8, n0 = bxi << 8;

  const int srow = lane >> 3;                  // row within 8-row gload strip
  const int ssw = ((lane & 7) ^ srow) * 8;     // preswizzled short offset in 128B row

  const short* Abase = A + (size_t)(m0 + srow) * K + ssw;
  const short* Bbase = Bt + (size_t)(n0 + srow) * K + ssw;

  auto STAGE_A = [&](int j) {                  // half-index j: K-tile j>>1, half j&1
    const int jc = (j > 2 * NT - 1) ? (2 * NT - 1) : j;   // tail: dummy (slot never re-read)
    const int slot = j & 3, k0 = (jc >> 1) * 64, r0 = (jc & 1) * 128;
    #pragma unroll
    for (int i = 0; i < 2; ++i) {
      const int rr = i * 64 + w * 8;
      gload_lds16(Abase + (size_t)(r0 + rr) * K + k0, (char*)&Ah[slot][0] + rr * 128);
    }
  };
  auto STAGE_B = [&](int j) {
    const int jc = (j > 2 * NT - 1) ? (2 * NT - 1) : j;
    const int slot = j & 3, k0 = (jc >> 1) * 64, c0 = (jc & 1) * 128;
    #pragma unroll
    for (int i = 0; i < 2; ++i) {
      const int rr = i * 64 + w * 8;
      gload_lds16(Bbase + (size_t)(c0 + rr) * K + k0, (char*)&Bh[slot][0] + rr * 128);
    }
  };

  const int arow = wr * 64 + r16;              // row within A slot (+ mf*16)
  const int brow = wc * 32 + r16;              // col within B slot (+ nf*16)
  const int swz7 = r16 & 7;

  v8s ar[4][2], br0[2][2], br1[2][2];
  auto LDA = [&](int slot) {
    const char* base = (const char*)&Ah[slot][0];
    #pragma unroll
    for (int mf = 0; mf < 4; ++mf)
      #pragma unroll
      for (int kh = 0; kh < 2; ++kh)
        ar[mf][kh] = *(const v8s*)(base + (arow + mf * 16) * 128 + (((kh * 4 + g) ^ swz7) * 16));
  };
  auto LDB0 = [&](int slot) {
    const char* base = (const char*)&Bh[slot][0];
    #pragma unroll
    for (int nf = 0; nf < 2; ++nf)
      #pragma unroll
      for (int kh = 0; kh < 2; ++kh)
        br0[nf][kh] = *(const v8s*)(base + (brow + nf * 16) * 128 + (((kh * 4 + g) ^ swz7) * 16));
  };
  auto LDB1 = [&](int slot) {
    const char* base = (const char*)&Bh[slot][0];
    #pragma unroll
    for (int nf = 0; nf < 2; ++nf)
      #pragma unroll
      for (int kh = 0; kh < 2; ++kh)
        br1[nf][kh] = *(const v8s*)(base + (brow + nf * 16) * 128 + (((kh * 4 + g) ^ swz7) * 16));
  };

  v4f acc[2][2][4][2] = {};   // [qm][qn][mf][nf]

#define MMA_Q(QM, QN, BR)                                                      \
  do {                                                                         \
    __builtin_amdgcn_s_setprio(1);                                             \
    _Pragma("unroll")                                                          \
    for (int kh = 0; kh < 2; ++kh)                                             \
      _Pragma("unroll")                                                        \
      for (int mf = 0; mf < 4; ++mf)                                           \
        _Pragma("unroll")                                                      \
        for (int nf = 0; nf < 2; ++nf)                                         \
          acc[QM][QN][mf][nf] = MFMA(ar[mf][kh], BR[nf][kh], acc[QM][QN][mf][nf]); \
    __builtin_amdgcn_s_setprio(0);                                             \
  } while (0)

  STAGE_A(0); STAGE_B(0); STAGE_B(1); STAGE_A(1); STAGE_A(2); STAGE_B(2); STAGE_B(3);
  VMW(6);
  BAR;

  auto KTILE = [&](int T, int sa) {
    // ---- P0: quadrant (0,0)
    LDA(sa); LDB0(sa);
    STAGE_A(2 * T + 3);
    BAR;
    MMA_Q(0, 0, br0);
    BAR;
    // ---- P1: quadrant (0,1)
    LDB1(sa + 1);
    BAR;
    MMA_Q(0, 1, br1);
    BAR;
    // ---- P2: quadrant (1,1)
    LDA(sa + 1);
    STAGE_A(2 * T + 4); STAGE_B(2 * T + 4);
    BAR;
    MMA_Q(1, 1, br1);
    BAR;
    // ---- P3: quadrant (1,0)
    STAGE_B(2 * T + 5);
    BAR;
    MMA_Q(1, 0, br0);
    VMW(6);   // retires exactly T+1's 4 half-tiles; 3 newest stay in flight
    BAR;
  };

  #pragma unroll
  for (int t2 = 0; t2 < NT / 2; ++t2) {
    KTILE(2 * t2, 0);
    KTILE(2 * t2 + 1, 2);
  }
#undef MMA_Q

  // ---- epilogue
  if constexpr (MODE == 3) {
    if (n0 >= 1024) {
      // V column-block: write kappa^{-1}-permuted V^T into Vt only.
      const int bb = m0 >> 11;                       // batch (block spans one batch)
      const int cperm = 16 * (g >> 1) + 8 * (g & 1); // g-dependent column bits
      #pragma unroll
      for (int qm = 0; qm < 2; ++qm)
        #pragma unroll
        for (int mf = 0; mf < 4; ++mf) {
          const int key0 = m0 + qm * 128 + wr * 64 + mf * 16;   // 16-aligned group base
          const int ng = (key0 & 2047) & ~63;                   // 64-group within seq
          // key bits: k5k4 = mf, k3k2 = g, k1k0 = r  ->  c = 32*(mf>>1)+16*(g>>1)+8*(g&1)+4*(mf&1)
          const int ccol = 32 * (mf >> 1) + cperm + 4 * (mf & 1);
          #pragma unroll
          for (int qn = 0; qn < 2; ++qn)
            #pragma unroll
            for (int nf = 0; nf < 2; ++nf) {
              const int col = n0 + qn * 128 + wc * 32 + nf * 16 + r16;
              const int dhg = col - 1024;
              const int bh = bb * 8 + (dhg >> 6);
              short* dst = Vt + (size_t)(bh * 64 + (dhg & 63)) * VTP + ng + ccol;
              uint2 st;
              st.x = (unsigned)(unsigned short)f2bf(acc[qm][qn][mf][nf][0]) |
                     ((unsigned)(unsigned short)f2bf(acc[qm][qn][mf][nf][1]) << 16);
              st.y = (unsigned)(unsigned short)f2bf(acc[qm][qn][mf][nf][2]) |
                     ((unsigned)(unsigned short)f2bf(acc[qm][qn][mf][nf][3]) << 16);
              *(uint2*)dst = st;
            }
        }
      return;
    }
  }
  #pragma unroll
  for (int qm = 0; qm < 2; ++qm)
    #pragma unroll
    for (int mf = 0; mf < 4; ++mf) {
      const int row = m0 + qm * 128 + wr * 64 + mf * 16 + g * 4;
      #pragma unroll
      for (int qn = 0; qn < 2; ++qn)
        #pragma unroll
        for (int nf = 0; nf < 2; ++nf) {
          const int col = n0 + qn * 128 + wc * 32 + nf * 16 + r16;
          float bv = 0.0f;
          if constexpr (MODE == 1) bv = bias[col];
          #pragma unroll
          for (int r = 0; r < 4; ++r) {
            float val = acc[qm][qn][mf][nf][r] + bv;
            if constexpr (MODE == 1) {
              const float z = val * 0.70710678118f;
              const float az = fabsf(z);
              const float t = 1.0f / (1.0f + 0.3275911f * az);
              const float p =
                  0.254829592f +
                  t * (-0.284496736f + t * (1.421413741f + t * (-1.453152027f + t * 1.061405429f)));
              float er = 1.0f - p * t * __expf(-az * az);
              er = (z < 0.0f) ? -er : er;
              val = 0.5f * val * (1.0f + er);
            }
            ((short*)Out)[(size_t)(row + r) * Nc + col] = f2bf(val);
          }
        }
    }
}

// ---------------------------------------------------------------- GEMM: C = A[M,K] * Bt[Nc,K]^T
// (R4 version — 2-deep + __syncthreads; R6's counted-vmcnt variant measured worse.)
template <int MODE, int BN>
__launch_bounds__(256)
__global__ void gemm128_kernel(const short* __restrict__ A, const short* __restrict__ Bt,
                               const float* __restrict__ bias, const float* __restrict__ Xres,
                               void* __restrict__ Out, int M, int Nc, int K) {
  constexpr int MR = (BN == 128) ? 4 : 2;
  __shared__ __align__(16) short As[2][128 * 64];   // [buf][row][64 shorts], chunk-swizzled
  __shared__ __align__(16) short Bs[2][BN * 64];
  const int tid = threadIdx.x;
  const int lane = tid & 63;
  const int w = tid >> 6;
  const int wr = (BN == 128) ? (w >> 1) : w;
  const int wc = (BN == 128) ? (w & 1) : 0;
  const int r16 = lane & 15, g = lane >> 4;

  const int nxb = Nc / BN;
  const int nyb = M >> 7;
  const int bid = (int)blockIdx.x;
  const int xcd = bid & 7;
  const int ii = bid >> 3;
  const int byi = xcd * (nyb >> 3) + ii / nxb;
  const int bxi = ii % nxb;
  const int m0 = byi * 128, n0 = bxi * BN;

  const int srow = lane >> 3;                  // row within 8-row gload
  const int ssw = ((lane & 7) ^ srow) * 8;     // preswizzled short offset within 128B row

  auto STAGE = [&](int buf, int k0) {
    #pragma unroll
    for (int j = 0; j < 4; ++j) {              // A: 128 rows, 4 instr/wave
      const int row = w * 32 + j * 8;
      gload_lds16(A + (size_t)(m0 + row + srow) * K + k0 + ssw,
                  (char*)&As[buf][0] + row * 128);
    }
    #pragma unroll
    for (int j = 0; j < BN / 32; ++j) {        // B: BN rows, BN/32 instr/wave
      const int row = w * (BN / 4) + j * 8;
      gload_lds16(Bt + (size_t)(n0 + row + srow) * K + k0 + ssw,
                  (char*)&Bs[buf][0] + row * 128);
    }
  };

  v4f acc[MR][4] = {};

  STAGE(0, 0);
  __syncthreads();   // prefetch 0 landed
  int cur = 0;
  for (int k0 = 0; k0 < K; k0 += 64) {
    if (k0 + 64 < K) STAGE(cur ^ 1, k0 + 64);   // overlap with compute below
    v8s af[MR][2], bf[4][2];
    #pragma unroll
    for (int m = 0; m < MR; ++m) {
      const int row = wr * (MR * 16) + m * 16 + r16;
      #pragma unroll
      for (int kh = 0; kh < 2; ++kh)
        af[m][kh] = *(const v8s*)((const char*)&As[cur][0] + row * 128 +
                                  (((kh * 4 + g) ^ (row & 7)) * 16));
    }
    #pragma unroll
    for (int n = 0; n < 4; ++n) {
      const int row = wc * 64 + n * 16 + r16;
      #pragma unroll
      for (int kh = 0; kh < 2; ++kh)
        bf[n][kh] = *(const v8s*)((const char*)&Bs[cur][0] + row * 128 +
                                  (((kh * 4 + g) ^ (row & 7)) * 16));
    }
    #pragma unroll
    for (int kh = 0; kh < 2; ++kh)
      #pragma unroll
      for (int m = 0; m < MR; ++m)
        #pragma unroll
        for (int n = 0; n < 4; ++n)
          acc[m][n] = MFMA(af[m][kh], bf[n][kh], acc[m][n]);
    __syncthreads();   // drains vmcnt (next buf ready) + fences LDS reuse
    cur ^= 1;
  }

  #pragma unroll
  for (int m = 0; m < MR; ++m) {
    const int row = m0 + wr * (MR * 16) + m * 16 + g * 4;
    #pragma unroll
    for (int n = 0; n < 4; ++n) {
      const int col = n0 + wc * 64 + n * 16 + r16;
      const float bv = bias ? bias[col] : 0.0f;
      #pragma unroll
      for (int r = 0; r < 4; ++r) {
        const size_t idx = (size_t)(row + r) * Nc + col;
        float val = acc[m][n][r] + bv;
        if constexpr (MODE == 0) {
          ((short*)Out)[idx] = f2bf(val);
        } else if constexpr (MODE == 1) {
          const float z = val * 0.70710678118f;
          const float az = fabsf(z);
          const float t = 1.0f / (1.0f + 0.3275911f * az);
          const float p =
              0.254829592f +
              t * (-0.284496736f + t * (1.421413741f + t * (-1.453152027f + t * 1.061405429f)));
          float er = 1.0f - p * t * __expf(-az * az);
          er = (z < 0.0f) ? -er : er;
          val = 0.5f * val * (1.0f + er);
          ((short*)Out)[idx] = f2bf(val);
        } else {
          ((float*)Out)[idx] = val + Xres[idx];
        }
      }
    }
  }
}

// ---------------------------------------------------------------- causal flash attention v17
// v13 schedule (Ks 3-deep + Vs 2-deep, counted vmcnt, grid 1024, 4 blocks/CU)
// with waves split over (q-half x key-half): wave w -> q rows (w&1)*32..+31,
// key half ko=(w>>1)*32 of every 64-key tile. Per tile per wave the LDS reads
// HALVE (kf 4 + vf 4 ds_read_b128 vs 16) while MFMA/exp counts, staging, the
// conflict-free r16 pattern, and TLP are unchanged (R7 lost TLP; R8 put L2
// latency on the critical path; this does neither). Masking stays the uniform
// key>qrow test (kbase+=ko): the fully-future key-half at the diagonal tile
// self-masks to zero via __expf(-3e38)=0. End: cross-wave partial-O/lsum
// reduce through the then-free Ks LDS (once per block).
__launch_bounds__(256)
__global__ void attn_kernel(const short* __restrict__ qkv, const short* __restrict__ Vt,
                            short* __restrict__ o) {
  __shared__ __align__(16) short Ks[3][64 * 64];   // key-major, XOR-swizzled
  __shared__ __align__(16) short Vs[2][64 * 64];   // dh-major,  XOR-swizzled
  const int lin = (int)blockIdx.x;
  const int bh = ((lin >> 3) & 3) * 8 + (lin & 7);
  const int xl2 = 31 - (lin >> 5);
  const int b = bh >> 3, h = bh & 7;
  const int q0 = xl2 * 64;
  const int tid = threadIdx.x, lane = tid & 63, w = tid >> 6;
  const int r16 = lane & 15, g = lane >> 4;
  const int qw = q0 + (w & 1) * 32;              // wave's 32 q-rows (2 subtiles)
  const int ko = (w >> 1) * 32;                  // wave's key half within each tile
  const int kc = w >> 1;                         // V chain index for this key half

  v8s qa0, qa1, qb0, qb1;
  {
    const size_t qA = ((size_t)(b * N + qw + r16)) * 1536 + h * 64;        // q sub A
    const size_t qB = ((size_t)(b * N + qw + 16 + r16)) * 1536 + h * 64;   // q sub B
    qa0 = *(const v8s*)(qkv + qA + g * 8);        // prescaled 1/8
    qa1 = *(const v8s*)(qkv + qA + 32 + g * 8);
    qb0 = *(const v8s*)(qkv + qB + g * 8);
    qb1 = *(const v8s*)(qkv + qB + 32 + g * 8);
  }

  const short* vtb = Vt + (size_t)bh * 64 * VTP;

  const int srow = lane >> 3;                    // row within staging instruction
  const int ssw = ((lane & 7) ^ srow) * 8;       // XOR-preswizzled short offset in row

  v4f oaccA[4] = {}, oaccB[4] = {};              // O partial (this key half)
  float lsumA = 0.f, lsumB = 0.f;
  const int tdiag = xl2;

  auto STAGE_K = [&](int t) {
    t = (t > tdiag) ? tdiag : t;                 // tail clamp (same-value dup)
    const int k0 = t * 64, buf = t % 3;
    #pragma unroll
    for (int j = 0; j < 2; ++j) {
      const int row = w * 16 + j * 8;
      gload_lds16(qkv + ((size_t)(b * N + k0 + row + srow)) * 1536 + 512 + h * 64 + ssw,
                  (char*)&Ks[buf][0] + row * 128);
    }
  };
  auto STAGE_V = [&](int t) {
    t = (t > tdiag) ? tdiag : t;
    const int k0 = t * 64, buf = t & 1;
    #pragma unroll
    for (int j = 0; j < 2; ++j) {
      const int row = w * 16 + j * 8;
      gload_lds16(vtb + (size_t)(row + srow) * VTP + k0 + ssw,
                  (char*)&Vs[buf][0] + row * 128);
    }
  };

  // prologue: K(0), V(0), K(1) -> queue holds 6 loads, VMW(2) in tile 0 retires K0,V0
  STAGE_K(0); STAGE_V(0); STAGE_K(1);

  for (int t = 0; t <= tdiag; ++t) {
    VMW(2);
    BAR;               // all waves: tile-t K/V landed; prev buffers free for overwrite
    STAGE_V(t + 1);
    STAGE_K(t + 2);

    const char* kb = (const char*)&Ks[t % 3][0];
    const char* vb = (const char*)&Vs[t & 1][0];

    // V fragments for this wave's key half only (4 x ds_read_b128)
    v8s vf[4];
    #pragma unroll
    for (int a = 0; a < 4; ++a)
      vf[a] = *(const v8s*)(vb + (a * 16 + r16) * 128 + (((kc * 4 + g) ^ (r16 & 7)) * 16));

    // --- S^T = K * Q^T over this key half, both q subtiles (kf loaded once) ---
    __builtin_amdgcn_s_setprio(1);
    v4f sA[2], sB[2];
    #pragma unroll
    for (int kt = 0; kt < 2; ++kt) {
      const int krow = (ko + kt * 16 + r16) * 128;
      v8s kfa = *(const v8s*)(kb + krow + ((g ^ (r16 & 7)) * 16));
      v8s kfb = *(const v8s*)(kb + krow + (((4 + g) ^ (r16 & 7)) * 16));
      v4f ss = {};
      ss = MFMA(kfa, qa0, ss);
      ss = MFMA(kfb, qa1, ss);
      sA[kt] = ss;
      v4f st = {};
      st = MFMA(kfa, qb0, st);
      st = MFMA(kfb, qb1, st);
      sB[kt] = st;
    }
    __builtin_amdgcn_s_setprio(0);

    // --- softmax numerators in registers (scale pre-folded into Q) ---
    const bool needmask = (t == tdiag);
    const int qrowA = qw + r16;
    const int qrowB = qw + 16 + r16;
    const int kbase = t * 64 + ko + 4 * g;
    unsigned pwA[4], pwB[4];
    #pragma unroll
    for (int kt = 0; kt < 2; ++kt) {
      float eA[4], eB[4];
      #pragma unroll
      for (int r = 0; r < 4; ++r) {
        const int key = kbase + kt * 16 + r;
        float va = sA[kt][r], vb2 = sB[kt][r];
        if (needmask) {
          if (key > qrowA) va = -3e38f;
          if (key > qrowB) vb2 = -3e38f;
        }
        eA[r] = __expf(va);
        eB[r] = __expf(vb2);
      }
      lsumA += (eA[0] + eA[1]) + (eA[2] + eA[3]);
      lsumB += (eB[0] + eB[1]) + (eB[2] + eB[3]);
      pwA[kt * 2 + 0] = pack2bf_t(eA[0], eA[1]);
      pwA[kt * 2 + 1] = pack2bf_t(eA[2], eA[3]);
      pwB[kt * 2 + 0] = pack2bf_t(eB[0], eB[1]);
      pwB[kt * 2 + 1] = pack2bf_t(eB[2], eB[3]);
    }
    union PU { unsigned u[4]; v8s s8; };
    PU pA, pB;
    pA.u[0] = pwA[0]; pA.u[1] = pwA[1]; pA.u[2] = pwA[2]; pA.u[3] = pwA[3];
    pB.u[0] = pwB[0]; pB.u[1] = pwB[1]; pB.u[2] = pwB[2]; pB.u[3] = pwB[3];

    // --- O += P * V (one K=32 chain: this wave's key half) ---
    __builtin_amdgcn_s_setprio(1);
    #pragma unroll
    for (int dt = 0; dt < 4; ++dt) {
      oaccA[dt] = MFMA(pA.s8, vf[dt], oaccA[dt]);
      oaccB[dt] = MFMA(pB.s8, vf[dt], oaccB[dt]);
    }
    __builtin_amdgcn_s_setprio(0);
  }

  // ---- cross-wave reduce: waves (0,2) share q-half 0, (1,3) share q-half 1 ----
  // Ks (24KB) is free now; 2 regions x 64 lanes x 34 floats = 17408B.
  float* red = (float*)&Ks[0][0];
  BAR;   // everyone done with staging buffers
  if (w >= 2) {
    float* mine = red + (size_t)(w - 2) * (64 * 34) + lane * 34;
    #pragma unroll
    for (int dt = 0; dt < 4; ++dt)
      #pragma unroll
      for (int r = 0; r < 4; ++r) {
        mine[dt * 4 + r] = oaccA[dt][r];
        mine[16 + dt * 4 + r] = oaccB[dt][r];
      }
    mine[32] = lsumA;
    mine[33] = lsumB;
  }
  BAR;
  if (w < 2) {
    const float* p = red + (size_t)w * (64 * 34) + lane * 34;
    #pragma unroll
    for (int dt = 0; dt < 4; ++dt)
      #pragma unroll
      for (int r = 0; r < 4; ++r) {
        oaccA[dt][r] += p[dt * 4 + r];
        oaccB[dt][r] += p[16 + dt * 4 + r];
      }
    lsumA += p[32];
    lsumB += p[33];

    // reduce the 4 g-replicas of each q-row, redistribute, store
    lsumA += __shfl_xor(lsumA, 16, 64);
    lsumA += __shfl_xor(lsumA, 32, 64);
    lsumB += __shfl_xor(lsumB, 16, 64);
    lsumB += __shfl_xor(lsumB, 32, 64);
    const float linvA = 1.0f / lsumA;
    const float linvB = 1.0f / lsumB;
    float ldA[4], ldB[4];
    #pragma unroll
    for (int r = 0; r < 4; ++r) {
      ldA[r] = __shfl(linvA, g * 4 + r, 64);
      ldB[r] = __shfl(linvB, g * 4 + r, 64);
    }
    #pragma unroll
    for (int dt = 0; dt < 4; ++dt)
      #pragma unroll
      for (int r = 0; r < 4; ++r) {
        o[((size_t)(b * N + qw + g * 4 + r)) * 512 + h * 64 + dt * 16 + r16] =
            f2bf(oaccA[dt][r] * ldA[r]);
        o[((size_t)(b * N + qw + 16 + g * 4 + r)) * 512 + h * 64 + dt * 16 + r16] =
            f2bf(oaccB[dt][r] * ldB[r]);
      }
  }
}

// ----------------------------------------------------------------------------
extern "C" void kernel_launch(void* const* d_in, const int* in_sizes, int n_in,
                              void* d_out, int out_size, void* d_ws, size_t ws_size,
                              hipStream_t stream) {
  const float* x_in  = (const float*)d_in[0];
  // d_in[1] = mask (strict causal — baked into attn_kernel)
  const float* ln1_w = (const float*)d_in[2];
  const float* ln1_b = (const float*)d_in[3];
  const float* w_qkv = (const float*)d_in[4];
  const float* w_out = (const float*)d_in[5];
  const float* b_out = (const float*)d_in[6];
  const float* ln2_w = (const float*)d_in[7];
  const float* ln2_b = (const float*)d_in[8];
  const float* w1    = (const float*)d_in[9];
  const float* b1    = (const float*)d_in[10];
  const float* w2    = (const float*)d_in[11];
  const float* b2    = (const float*)d_in[12];

  char* ws = (char*)d_ws;
  size_t off = 0;
  auto alloc = [&](size_t bytes) { char* p = ws + off; off += (bytes + 255) & ~(size_t)255; return p; };
  short* wqkvT = (short*)alloc((size_t)L * 1536 * 512 * 2);
  short* woutT = (short*)alloc((size_t)L * 512 * 512 * 2);
  short* w1T   = (short*)alloc((size_t)L * 512 * 2048 * 2);
  short* w2T   = (short*)alloc((size_t)L * 2048 * 512 * 2);
  short* hln   = (short*)alloc((size_t)M_ROWS * 512 * 2);
  short* big   = (short*)alloc((size_t)M_ROWS * 2048 * 2);  // qkv (1536 cols) & ff (2048 cols) share
  short* oatt  = (short*)alloc((size_t)M_ROWS * 512 * 2);
  short* Vtg   = (short*)alloc((size_t)BATCH * H * 64 * VTP * 2);
  short* qkv = big;
  short* ff  = big;

  float* x = (float*)d_out;   // fp32 residual stream lives in d_out
  // No upfront copy: layer 0 reads x_in directly (ln1 + out-proj residual);
  // out-proj MODE 2 writes ALL of x before anything reads it.

  transpose_w_kernel<<<dim3(1536 / 32, 512 / 32, L), 256, 0, stream>>>(w_qkv, wqkvT, 512, 1536, 512);
  transpose_w_kernel<<<dim3(512 / 32, 512 / 32, L), 256, 0, stream>>>(w_out, woutT, 512, 512, 0);
  transpose_w_kernel<<<dim3(2048 / 32, 512 / 32, L), 256, 0, stream>>>(w1, w1T, 512, 2048, 0);
  transpose_w_kernel<<<dim3(512 / 32, 2048 / 32, L), 256, 0, stream>>>(w2, w2T, 2048, 512, 0);

  for (int l = 0; l < L; ++l) {
    const float* xl = (l == 0) ? x_in : x;   // residual state entering this layer
    // --- attention block ---
    ln_kernel<<<M_ROWS / 4, 256, 0, stream>>>(xl, ln1_w + l * 512, ln1_b + l * 512, hln);
    gemm256_kernel<3, 8><<<dim3((1536 / 256) * (M_ROWS / 256)), 512, 0, stream>>>(
        hln, wqkvT + (size_t)l * 1536 * 512, nullptr, qkv, Vtg, M_ROWS, 1536);
    attn_kernel<<<dim3(1024), 256, 0, stream>>>(qkv, Vtg, oatt);
    gemm128_kernel<2, 64><<<dim3((512 / 64) * (M_ROWS / 128)), 256, 0, stream>>>(
        oatt, woutT + (size_t)l * 512 * 512, b_out + l * 512, xl, x, M_ROWS, 512, 512);
    // --- MLP block ---
    ln_kernel<<<M_ROWS / 4, 256, 0, stream>>>(x, ln2_w + l * 512, ln2_b + l * 512, hln);
    gemm256_kernel<1, 8><<<dim3((2048 / 256) * (M_ROWS / 256)), 512, 0, stream>>>(
        hln, w1T + (size_t)l * 512 * 2048, b1 + l * 2048, ff, nullptr, M_ROWS, 2048);
    gemm128_kernel<2, 64><<<dim3((512 / 64) * (M_ROWS / 128)), 256, 0, stream>>>(
        ff, w2T + (size_t)l * 2048 * 512, b2 + l * 512, x, x, M_ROWS, 512, 2048);
  }
}

// Round 12
// 585.045 us; speedup vs baseline: 1.1866x; 1.0119x over previous
//
#include <hip/hip_runtime.h>
#include <math.h>

#define L 4
#define BATCH 4
#define N 2048
#define D 512
#define H 8
#define DH 64
#define MLPD 2048
#define M_ROWS (BATCH * N)  // 8192
#define VTP 2064            // V^T row pitch (shorts): 2048 + 16 to break 4KB aliasing

using v8s = __attribute__((ext_vector_type(8))) short;   // 8 x bf16
using v4f = __attribute__((ext_vector_type(4))) float;

__device__ inline short f2bf(float f) {
  union { float f; unsigned u; } v; v.f = f;
  unsigned r = v.u + 0x7FFFu + ((v.u >> 16) & 1u);   // RNE
  return (short)(r >> 16);
}
__device__ inline unsigned pack2bf_t(float a, float b) {   // truncating pack (P only)
  union { float f; unsigned u; } x, y; x.f = a; y.f = b;
  return (x.u >> 16) | (y.u & 0xFFFF0000u);
}

#define MFMA(a, b, c) __builtin_amdgcn_mfma_f32_16x16x32_bf16(a, b, c, 0, 0, 0)

// async 16B/lane global->LDS (dest = wave-uniform base + lane*16; SOURCE is per-lane)
__device__ __forceinline__ void gload_lds16(const void* g, void* l) {
  __builtin_amdgcn_global_load_lds((const __attribute__((address_space(1))) void*)g,
                                   (__attribute__((address_space(3))) void*)l, 16, 0, 0);
}

// compiler-motion fences / raw barrier / counted vmem wait
#define FENCE asm volatile("" ::: "memory")
#define BAR  do { FENCE; __builtin_amdgcn_s_barrier(); FENCE; } while (0)
#define VMW(n) asm volatile("s_waitcnt vmcnt(" #n ")" ::: "memory")

// ------------------------------------------------- all 4 weight transposes, ONE launch
// fp32 [R][C] -> bf16 [C][R] per layer z; wqkv's first 512 output rows (Q cols)
// scaled by 0.125 (exact bf16 exponent shift — folds attention 1/sqrt(DH)).
// Job table (compile-time): blocks [0,3072) wqkv, [3072,4096) wout,
// [4096,8192) w1, [8192,12288) w2.
__launch_bounds__(256)
__global__ void transpose_all_kernel(const float* __restrict__ wqkv, short* __restrict__ wqkvT,
                                     const float* __restrict__ wout, short* __restrict__ woutT,
                                     const float* __restrict__ w1, short* __restrict__ w1T,
                                     const float* __restrict__ w2, short* __restrict__ w2T) {
  __shared__ float tile[32][33];
  const int bid = (int)blockIdx.x;
  const float* src; short* dst; int R, C, qcols, tpz, idx;
  if (bid < 3072)      { src = wqkv; dst = wqkvT; R = 512;  C = 1536; qcols = 512; tpz = 768;  idx = bid; }
  else if (bid < 4096) { src = wout; dst = woutT; R = 512;  C = 512;  qcols = 0;   tpz = 256;  idx = bid - 3072; }
  else if (bid < 8192) { src = w1;   dst = w1T;   R = 512;  C = 2048; qcols = 0;   tpz = 1024; idx = bid - 4096; }
  else                 { src = w2;   dst = w2T;   R = 2048; C = 512;  qcols = 0;   tpz = 1024; idx = bid - 8192; }
  const int z = idx / tpz, rem = idx % tpz;
  const int nx = C >> 5;
  const int c0 = (rem % nx) * 32, r0 = (rem / nx) * 32;
  const size_t base = (size_t)z * R * C;
  const int tx = threadIdx.x & 31, ty = threadIdx.x >> 5;   // 32 x 8
  #pragma unroll
  for (int i = ty; i < 32; i += 8)
    tile[i][tx] = src[base + (size_t)(r0 + i) * C + c0 + tx];
  __syncthreads();
  #pragma unroll
  for (int i = ty; i < 32; i += 8) {
    float val = tile[tx][i];
    if (c0 + i < qcols) val *= 0.125f;
    dst[base + (size_t)(c0 + i) * R + r0 + tx] = f2bf(val);
  }
}

// ---------------------------------------------------------------- LayerNorm (wave per row)
__launch_bounds__(256)
__global__ void ln_kernel(const float* __restrict__ x, const float* __restrict__ w,
                          const float* __restrict__ b, short* __restrict__ out) {
  const int row = blockIdx.x * 4 + (threadIdx.x >> 6);
  const int lane = threadIdx.x & 63;
  const float* xr = x + (size_t)row * D;
  float4 a0 = *(const float4*)(xr + lane * 8);
  float4 a1 = *(const float4*)(xr + lane * 8 + 4);
  float v[8] = {a0.x, a0.y, a0.z, a0.w, a1.x, a1.y, a1.z, a1.w};
  float s = 0.f;
  #pragma unroll
  for (int j = 0; j < 8; ++j) s += v[j];
  #pragma unroll
  for (int m = 1; m < 64; m <<= 1) s += __shfl_xor(s, m, 64);
  const float mean = s * (1.0f / D);
  float q = 0.f;
  #pragma unroll
  for (int j = 0; j < 8; ++j) { float d = v[j] - mean; q += d * d; }
  #pragma unroll
  for (int m = 1; m < 64; m <<= 1) q += __shfl_xor(q, m, 64);
  const float rstd = rsqrtf(q * (1.0f / D) + 1e-5f);
  float4 w0 = *(const float4*)(w + lane * 8);
  float4 w1 = *(const float4*)(w + lane * 8 + 4);
  float4 b0 = *(const float4*)(b + lane * 8);
  float4 b1 = *(const float4*)(b + lane * 8 + 4);
  float wv[8] = {w0.x, w0.y, w0.z, w0.w, w1.x, w1.y, w1.z, w1.w};
  float bv[8] = {b0.x, b0.y, b0.z, b0.w, b1.x, b1.y, b1.z, b1.w};
  v8s r;
  #pragma unroll
  for (int j = 0; j < 8; ++j) r[j] = f2bf((v[j] - mean) * rstd * wv[j] + bv[j]);
  *(v8s*)(out + (size_t)row * D + lane * 8) = r;
}

// ---------------------------------------------------------------- 256x256 8-phase GEMM
// (R1 notes) + R4 VMW(6) + tail source-clamped stages.
// MODE 0: bf16 out   1: bf16 gelu(out+bias)
// MODE 3: qkv fused epilogue — V column-blocks (n0>=1024) written transposed +
//   kappa^{-1}-permuted into Vt ONLY; Q/K blocks take the normal bf16 path.
template <int MODE, int NT>   // K = NT*64
__launch_bounds__(512, 2)
__global__ void gemm256_kernel(const short* __restrict__ A, const short* __restrict__ Bt,
                               const float* __restrict__ bias, void* __restrict__ Out,
                               short* __restrict__ Vt, int M, int Nc) {
  constexpr int K = NT * 64;
  __shared__ __align__(16) short Ah[4][128 * 64];
  __shared__ __align__(16) short Bh[4][128 * 64];
  const int tid = threadIdx.x, lane = tid & 63, w = tid >> 6;
  const int wr = w >> 2, wc = w & 3;          // 2M x 4N wave grid
  const int r16 = lane & 15, g = lane >> 4;

  const int nxb = Nc >> 8;
  const int nyb = M >> 8;
  const int bid = (int)blockIdx.x;
  const int xcd = bid & 7, ii = bid >> 3;
  const int byi = xcd * (nyb >> 3) + ii / nxb;
  const int bxi = ii % nxb;
  const int m0 = byi << 8, n0 = bxi << 8;

  const int srow = lane >> 3;                  // row within 8-row gload strip
  const int ssw = ((lane & 7) ^ srow) * 8;     // preswizzled short offset in 128B row

  const short* Abase = A + (size_t)(m0 + srow) * K + ssw;
  const short* Bbase = Bt + (size_t)(n0 + srow) * K + ssw;

  auto STAGE_A = [&](int j) {                  // half-index j: K-tile j>>1, half j&1
    const int jc = (j > 2 * NT - 1) ? (2 * NT - 1) : j;   // tail: dummy (slot never re-read)
    const int slot = j & 3, k0 = (jc >> 1) * 64, r0 = (jc & 1) * 128;
    #pragma unroll
    for (int i = 0; i < 2; ++i) {
      const int rr = i * 64 + w * 8;
      gload_lds16(Abase + (size_t)(r0 + rr) * K + k0, (char*)&Ah[slot][0] + rr * 128);
    }
  };
  auto STAGE_B = [&](int j) {
    const int jc = (j > 2 * NT - 1) ? (2 * NT - 1) : j;
    const int slot = j & 3, k0 = (jc >> 1) * 64, c0 = (jc & 1) * 128;
    #pragma unroll
    for (int i = 0; i < 2; ++i) {
      const int rr = i * 64 + w * 8;
      gload_lds16(Bbase + (size_t)(c0 + rr) * K + k0, (char*)&Bh[slot][0] + rr * 128);
    }
  };

  const int arow = wr * 64 + r16;              // row within A slot (+ mf*16)
  const int brow = wc * 32 + r16;              // col within B slot (+ nf*16)
  const int swz7 = r16 & 7;

  v8s ar[4][2], br0[2][2], br1[2][2];
  auto LDA = [&](int slot) {
    const char* base = (const char*)&Ah[slot][0];
    #pragma unroll
    for (int mf = 0; mf < 4; ++mf)
      #pragma unroll
      for (int kh = 0; kh < 2; ++kh)
        ar[mf][kh] = *(const v8s*)(base + (arow + mf * 16) * 128 + (((kh * 4 + g) ^ swz7) * 16));
  };
  auto LDB0 = [&](int slot) {
    const char* base = (const char*)&Bh[slot][0];
    #pragma unroll
    for (int nf = 0; nf < 2; ++nf)
      #pragma unroll
      for (int kh = 0; kh < 2; ++kh)
        br0[nf][kh] = *(const v8s*)(base + (brow + nf * 16) * 128 + (((kh * 4 + g) ^ swz7) * 16));
  };
  auto LDB1 = [&](int slot) {
    const char* base = (const char*)&Bh[slot][0];
    #pragma unroll
    for (int nf = 0; nf < 2; ++nf)
      #pragma unroll
      for (int kh = 0; kh < 2; ++kh)
        br1[nf][kh] = *(const v8s*)(base + (brow + nf * 16) * 128 + (((kh * 4 + g) ^ swz7) * 16));
  };

  v4f acc[2][2][4][2] = {};   // [qm][qn][mf][nf]

#define MMA_Q(QM, QN, BR)                                                      \
  do {                                                                         \
    __builtin_amdgcn_s_setprio(1);                                             \
    _Pragma("unroll")                                                          \
    for (int kh = 0; kh < 2; ++kh)                                             \
      _Pragma("unroll")                                                        \
      for (int mf = 0; mf < 4; ++mf)                                           \
        _Pragma("unroll")                                                      \
        for (int nf = 0; nf < 2; ++nf)                                         \
          acc[QM][QN][mf][nf] = MFMA(ar[mf][kh], BR[nf][kh], acc[QM][QN][mf][nf]); \
    __builtin_amdgcn_s_setprio(0);                                             \
  } while (0)

  STAGE_A(0); STAGE_B(0); STAGE_B(1); STAGE_A(1); STAGE_A(2); STAGE_B(2); STAGE_B(3);
  VMW(6);
  BAR;

  auto KTILE = [&](int T, int sa) {
    // ---- P0: quadrant (0,0)
    LDA(sa); LDB0(sa);
    STAGE_A(2 * T + 3);
    BAR;
    MMA_Q(0, 0, br0);
    BAR;
    // ---- P1: quadrant (0,1)
    LDB1(sa + 1);
    BAR;
    MMA_Q(0, 1, br1);
    BAR;
    // ---- P2: quadrant (1,1)
    LDA(sa + 1);
    STAGE_A(2 * T + 4); STAGE_B(2 * T + 4);
    BAR;
    MMA_Q(1, 1, br1);
    BAR;
    // ---- P3: quadrant (1,0)
    STAGE_B(2 * T + 5);
    BAR;
    MMA_Q(1, 0, br0);
    VMW(6);   // retires exactly T+1's 4 half-tiles; 3 newest stay in flight
    BAR;
  };

  #pragma unroll
  for (int t2 = 0; t2 < NT / 2; ++t2) {
    KTILE(2 * t2, 0);
    KTILE(2 * t2 + 1, 2);
  }
#undef MMA_Q

  // ---- epilogue
  if constexpr (MODE == 3) {
    if (n0 >= 1024) {
      // V column-block: write kappa^{-1}-permuted V^T into Vt only.
      const int bb = m0 >> 11;                       // batch (block spans one batch)
      const int cperm = 16 * (g >> 1) + 8 * (g & 1); // g-dependent column bits
      #pragma unroll
      for (int qm = 0; qm < 2; ++qm)
        #pragma unroll
        for (int mf = 0; mf < 4; ++mf) {
          const int key0 = m0 + qm * 128 + wr * 64 + mf * 16;   // 16-aligned group base
          const int ng = (key0 & 2047) & ~63;                   // 64-group within seq
          // key bits: k5k4 = mf, k3k2 = g, k1k0 = r  ->  c = 32*(mf>>1)+16*(g>>1)+8*(g&1)+4*(mf&1)
          const int ccol = 32 * (mf >> 1) + cperm + 4 * (mf & 1);
          #pragma unroll
          for (int qn = 0; qn < 2; ++qn)
            #pragma unroll
            for (int nf = 0; nf < 2; ++nf) {
              const int col = n0 + qn * 128 + wc * 32 + nf * 16 + r16;
              const int dhg = col - 1024;
              const int bh = bb * 8 + (dhg >> 6);
              short* dst = Vt + (size_t)(bh * 64 + (dhg & 63)) * VTP + ng + ccol;
              uint2 st;
              st.x = (unsigned)(unsigned short)f2bf(acc[qm][qn][mf][nf][0]) |
                     ((unsigned)(unsigned short)f2bf(acc[qm][qn][mf][nf][1]) << 16);
              st.y = (unsigned)(unsigned short)f2bf(acc[qm][qn][mf][nf][2]) |
                     ((unsigned)(unsigned short)f2bf(acc[qm][qn][mf][nf][3]) << 16);
              *(uint2*)dst = st;
            }
        }
      return;
    }
  }
  #pragma unroll
  for (int qm = 0; qm < 2; ++qm)
    #pragma unroll
    for (int mf = 0; mf < 4; ++mf) {
      const int row = m0 + qm * 128 + wr * 64 + mf * 16 + g * 4;
      #pragma unroll
      for (int qn = 0; qn < 2; ++qn)
        #pragma unroll
        for (int nf = 0; nf < 2; ++nf) {
          const int col = n0 + qn * 128 + wc * 32 + nf * 16 + r16;
          float bv = 0.0f;
          if constexpr (MODE == 1) bv = bias[col];
          #pragma unroll
          for (int r = 0; r < 4; ++r) {
            float val = acc[qm][qn][mf][nf][r] + bv;
            if constexpr (MODE == 1) {
              const float z = val * 0.70710678118f;
              const float az = fabsf(z);
              const float t = 1.0f / (1.0f + 0.3275911f * az);
              const float p =
                  0.254829592f +
                  t * (-0.284496736f + t * (1.421413741f + t * (-1.453152027f + t * 1.061405429f)));
              float er = 1.0f - p * t * __expf(-az * az);
              er = (z < 0.0f) ? -er : er;
              val = 0.5f * val * (1.0f + er);
            }
            ((short*)Out)[(size_t)(row + r) * Nc + col] = f2bf(val);
          }
        }
    }
}

// ---------------------------------------------------------------- GEMM: C = A[M,K] * Bt[Nc,K]^T
// (R4 version — 2-deep + __syncthreads; R6's counted-vmcnt variant measured worse.)
template <int MODE, int BN>
__launch_bounds__(256)
__global__ void gemm128_kernel(const short* __restrict__ A, const short* __restrict__ Bt,
                               const float* __restrict__ bias, const float* __restrict__ Xres,
                               void* __restrict__ Out, int M, int Nc, int K) {
  constexpr int MR = (BN == 128) ? 4 : 2;
  __shared__ __align__(16) short As[2][128 * 64];   // [buf][row][64 shorts], chunk-swizzled
  __shared__ __align__(16) short Bs[2][BN * 64];
  const int tid = threadIdx.x;
  const int lane = tid & 63;
  const int w = tid >> 6;
  const int wr = (BN == 128) ? (w >> 1) : w;
  const int wc = (BN == 128) ? (w & 1) : 0;
  const int r16 = lane & 15, g = lane >> 4;

  const int nxb = Nc / BN;
  const int nyb = M >> 7;
  const int bid = (int)blockIdx.x;
  const int xcd = bid & 7;
  const int ii = bid >> 3;
  const int byi = xcd * (nyb >> 3) + ii / nxb;
  const int bxi = ii % nxb;
  const int m0 = byi * 128, n0 = bxi * BN;

  const int srow = lane >> 3;                  // row within 8-row gload
  const int ssw = ((lane & 7) ^ srow) * 8;     // preswizzled short offset within 128B row

  auto STAGE = [&](int buf, int k0) {
    #pragma unroll
    for (int j = 0; j < 4; ++j) {              // A: 128 rows, 4 instr/wave
      const int row = w * 32 + j * 8;
      gload_lds16(A + (size_t)(m0 + row + srow) * K + k0 + ssw,
                  (char*)&As[buf][0] + row * 128);
    }
    #pragma unroll
    for (int j = 0; j < BN / 32; ++j) {        // B: BN rows, BN/32 instr/wave
      const int row = w * (BN / 4) + j * 8;
      gload_lds16(Bt + (size_t)(n0 + row + srow) * K + k0 + ssw,
                  (char*)&Bs[buf][0] + row * 128);
    }
  };

  v4f acc[MR][4] = {};

  STAGE(0, 0);
  __syncthreads();   // prefetch 0 landed
  int cur = 0;
  for (int k0 = 0; k0 < K; k0 += 64) {
    if (k0 + 64 < K) STAGE(cur ^ 1, k0 + 64);   // overlap with compute below
    v8s af[MR][2], bf[4][2];
    #pragma unroll
    for (int m = 0; m < MR; ++m) {
      const int row = wr * (MR * 16) + m * 16 + r16;
      #pragma unroll
      for (int kh = 0; kh < 2; ++kh)
        af[m][kh] = *(const v8s*)((const char*)&As[cur][0] + row * 128 +
                                  (((kh * 4 + g) ^ (row & 7)) * 16));
    }
    #pragma unroll
    for (int n = 0; n < 4; ++n) {
      const int row = wc * 64 + n * 16 + r16;
      #pragma unroll
      for (int kh = 0; kh < 2; ++kh)
        bf[n][kh] = *(const v8s*)((const char*)&Bs[cur][0] + row * 128 +
                                  (((kh * 4 + g) ^ (row & 7)) * 16));
    }
    #pragma unroll
    for (int kh = 0; kh < 2; ++kh)
      #pragma unroll
      for (int m = 0; m < MR; ++m)
        #pragma unroll
        for (int n = 0; n < 4; ++n)
          acc[m][n] = MFMA(af[m][kh], bf[n][kh], acc[m][n]);
    __syncthreads();   // drains vmcnt (next buf ready) + fences LDS reuse
    cur ^= 1;
  }

  #pragma unroll
  for (int m = 0; m < MR; ++m) {
    const int row = m0 + wr * (MR * 16) + m * 16 + g * 4;
    #pragma unroll
    for (int n = 0; n < 4; ++n) {
      const int col = n0 + wc * 64 + n * 16 + r16;
      const float bv = bias ? bias[col] : 0.0f;
      #pragma unroll
      for (int r = 0; r < 4; ++r) {
        const size_t idx = (size_t)(row + r) * Nc + col;
        float val = acc[m][n][r] + bv;
        if constexpr (MODE == 0) {
          ((short*)Out)[idx] = f2bf(val);
        } else if constexpr (MODE == 1) {
          const float z = val * 0.70710678118f;
          const float az = fabsf(z);
          const float t = 1.0f / (1.0f + 0.3275911f * az);
          const float p =
              0.254829592f +
              t * (-0.284496736f + t * (1.421413741f + t * (-1.453152027f + t * 1.061405429f)));
          float er = 1.0f - p * t * __expf(-az * az);
          er = (z < 0.0f) ? -er : er;
          val = 0.5f * val * (1.0f + er);
          ((short*)Out)[idx] = f2bf(val);
        } else {
          ((float*)Out)[idx] = val + Xres[idx];
        }
      }
    }
  }
}

// ---------------------------------------------------------------- causal flash attention v17
// (R10 measured-best: v13 schedule with waves split over q-half x key-half;
// per-tile LDS reads halved, TLP/grid/patterns unchanged; cross-wave partial-O
// reduce through the freed Ks LDS at the end.)
__launch_bounds__(256)
__global__ void attn_kernel(const short* __restrict__ qkv, const short* __restrict__ Vt,
                            short* __restrict__ o) {
  __shared__ __align__(16) short Ks[3][64 * 64];   // key-major, XOR-swizzled
  __shared__ __align__(16) short Vs[2][64 * 64];   // dh-major,  XOR-swizzled
  const int lin = (int)blockIdx.x;
  const int bh = ((lin >> 3) & 3) * 8 + (lin & 7);
  const int xl2 = 31 - (lin >> 5);
  const int b = bh >> 3, h = bh & 7;
  const int q0 = xl2 * 64;
  const int tid = threadIdx.x, lane = tid & 63, w = tid >> 6;
  const int r16 = lane & 15, g = lane >> 4;
  const int qw = q0 + (w & 1) * 32;              // wave's 32 q-rows (2 subtiles)
  const int ko = (w >> 1) * 32;                  // wave's key half within each tile
  const int kc = w >> 1;                         // V chain index for this key half

  v8s qa0, qa1, qb0, qb1;
  {
    const size_t qA = ((size_t)(b * N + qw + r16)) * 1536 + h * 64;        // q sub A
    const size_t qB = ((size_t)(b * N + qw + 16 + r16)) * 1536 + h * 64;   // q sub B
    qa0 = *(const v8s*)(qkv + qA + g * 8);        // prescaled 1/8
    qa1 = *(const v8s*)(qkv + qA + 32 + g * 8);
    qb0 = *(const v8s*)(qkv + qB + g * 8);
    qb1 = *(const v8s*)(qkv + qB + 32 + g * 8);
  }

  const short* vtb = Vt + (size_t)bh * 64 * VTP;

  const int srow = lane >> 3;                    // row within staging instruction
  const int ssw = ((lane & 7) ^ srow) * 8;       // XOR-preswizzled short offset in row

  v4f oaccA[4] = {}, oaccB[4] = {};              // O partial (this key half)
  float lsumA = 0.f, lsumB = 0.f;
  const int tdiag = xl2;

  auto STAGE_K = [&](int t) {
    t = (t > tdiag) ? tdiag : t;                 // tail clamp (same-value dup)
    const int k0 = t * 64, buf = t % 3;
    #pragma unroll
    for (int j = 0; j < 2; ++j) {
      const int row = w * 16 + j * 8;
      gload_lds16(qkv + ((size_t)(b * N + k0 + row + srow)) * 1536 + 512 + h * 64 + ssw,
                  (char*)&Ks[buf][0] + row * 128);
    }
  };
  auto STAGE_V = [&](int t) {
    t = (t > tdiag) ? tdiag : t;
    const int k0 = t * 64, buf = t & 1;
    #pragma unroll
    for (int j = 0; j < 2; ++j) {
      const int row = w * 16 + j * 8;
      gload_lds16(vtb + (size_t)(row + srow) * VTP + k0 + ssw,
                  (char*)&Vs[buf][0] + row * 128);
    }
  };

  // prologue: K(0), V(0), K(1) -> queue holds 6 loads, VMW(2) in tile 0 retires K0,V0
  STAGE_K(0); STAGE_V(0); STAGE_K(1);

  for (int t = 0; t <= tdiag; ++t) {
    VMW(2);
    BAR;               // all waves: tile-t K/V landed; prev buffers free for overwrite
    STAGE_V(t + 1);
    STAGE_K(t + 2);

    const char* kb = (const char*)&Ks[t % 3][0];
    const char* vb = (const char*)&Vs[t & 1][0];

    // V fragments for this wave's key half only (4 x ds_read_b128)
    v8s vf[4];
    #pragma unroll
    for (int a = 0; a < 4; ++a)
      vf[a] = *(const v8s*)(vb + (a * 16 + r16) * 128 + (((kc * 4 + g) ^ (r16 & 7)) * 16));

    // --- S^T = K * Q^T over this key half, both q subtiles (kf loaded once) ---
    __builtin_amdgcn_s_setprio(1);
    v4f sA[2], sB[2];
    #pragma unroll
    for (int kt = 0; kt < 2; ++kt) {
      const int krow = (ko + kt * 16 + r16) * 128;
      v8s kfa = *(const v8s*)(kb + krow + ((g ^ (r16 & 7)) * 16));
      v8s kfb = *(const v8s*)(kb + krow + (((4 + g) ^ (r16 & 7)) * 16));
      v4f ss = {};
      ss = MFMA(kfa, qa0, ss);
      ss = MFMA(kfb, qa1, ss);
      sA[kt] = ss;
      v4f st = {};
      st = MFMA(kfa, qb0, st);
      st = MFMA(kfb, qb1, st);
      sB[kt] = st;
    }
    __builtin_amdgcn_s_setprio(0);

    // --- softmax numerators in registers (scale pre-folded into Q) ---
    const bool needmask = (t == tdiag);
    const int qrowA = qw + r16;
    const int qrowB = qw + 16 + r16;
    const int kbase = t * 64 + ko + 4 * g;
    unsigned pwA[4], pwB[4];
    #pragma unroll
    for (int kt = 0; kt < 2; ++kt) {
      float eA[4], eB[4];
      #pragma unroll
      for (int r = 0; r < 4; ++r) {
        const int key = kbase + kt * 16 + r;
        float va = sA[kt][r], vb2 = sB[kt][r];
        if (needmask) {
          if (key > qrowA) va = -3e38f;
          if (key > qrowB) vb2 = -3e38f;
        }
        eA[r] = __expf(va);
        eB[r] = __expf(vb2);
      }
      lsumA += (eA[0] + eA[1]) + (eA[2] + eA[3]);
      lsumB += (eB[0] + eB[1]) + (eB[2] + eB[3]);
      pwA[kt * 2 + 0] = pack2bf_t(eA[0], eA[1]);
      pwA[kt * 2 + 1] = pack2bf_t(eA[2], eA[3]);
      pwB[kt * 2 + 0] = pack2bf_t(eB[0], eB[1]);
      pwB[kt * 2 + 1] = pack2bf_t(eB[2], eB[3]);
    }
    union PU { unsigned u[4]; v8s s8; };
    PU pA, pB;
    pA.u[0] = pwA[0]; pA.u[1] = pwA[1]; pA.u[2] = pwA[2]; pA.u[3] = pwA[3];
    pB.u[0] = pwB[0]; pB.u[1] = pwB[1]; pB.u[2] = pwB[2]; pB.u[3] = pwB[3];

    // --- O += P * V (one K=32 chain: this wave's key half) ---
    __builtin_amdgcn_s_setprio(1);
    #pragma unroll
    for (int dt = 0; dt < 4; ++dt) {
      oaccA[dt] = MFMA(pA.s8, vf[dt], oaccA[dt]);
      oaccB[dt] = MFMA(pB.s8, vf[dt], oaccB[dt]);
    }
    __builtin_amdgcn_s_setprio(0);
  }

  // ---- cross-wave reduce: waves (0,2) share q-half 0, (1,3) share q-half 1 ----
  // Ks (24KB) is free now; 2 regions x 64 lanes x 34 floats = 17408B.
  float* red = (float*)&Ks[0][0];
  BAR;   // everyone done with staging buffers
  if (w >= 2) {
    float* mine = red + (size_t)(w - 2) * (64 * 34) + lane * 34;
    #pragma unroll
    for (int dt = 0; dt < 4; ++dt)
      #pragma unroll
      for (int r = 0; r < 4; ++r) {
        mine[dt * 4 + r] = oaccA[dt][r];
        mine[16 + dt * 4 + r] = oaccB[dt][r];
      }
    mine[32] = lsumA;
    mine[33] = lsumB;
  }
  BAR;
  if (w < 2) {
    const float* p = red + (size_t)w * (64 * 34) + lane * 34;
    #pragma unroll
    for (int dt = 0; dt < 4; ++dt)
      #pragma unroll
      for (int r = 0; r < 4; ++r) {
        oaccA[dt][r] += p[dt * 4 + r];
        oaccB[dt][r] += p[16 + dt * 4 + r];
      }
    lsumA += p[32];
    lsumB += p[33];

    // reduce the 4 g-replicas of each q-row, redistribute, store
    lsumA += __shfl_xor(lsumA, 16, 64);
    lsumA += __shfl_xor(lsumA, 32, 64);
    lsumB += __shfl_xor(lsumB, 16, 64);
    lsumB += __shfl_xor(lsumB, 32, 64);
    const float linvA = 1.0f / lsumA;
    const float linvB = 1.0f / lsumB;
    float ldA[4], ldB[4];
    #pragma unroll
    for (int r = 0; r < 4; ++r) {
      ldA[r] = __shfl(linvA, g * 4 + r, 64);
      ldB[r] = __shfl(linvB, g * 4 + r, 64);
    }
    #pragma unroll
    for (int dt = 0; dt < 4; ++dt)
      #pragma unroll
      for (int r = 0; r < 4; ++r) {
        o[((size_t)(b * N + qw + g * 4 + r)) * 512 + h * 64 + dt * 16 + r16] =
            f2bf(oaccA[dt][r] * ldA[r]);
        o[((size_t)(b * N + qw + 16 + g * 4 + r)) * 512 + h * 64 + dt * 16 + r16] =
            f2bf(oaccB[dt][r] * ldB[r]);
      }
  }
}

// ----------------------------------------------------------------------------
extern "C" void kernel_launch(void* const* d_in, const int* in_sizes, int n_in,
                              void* d_out, int out_size, void* d_ws, size_t ws_size,
                              hipStream_t stream) {
  const float* x_in  = (const float*)d_in[0];
  // d_in[1] = mask (strict causal — baked into attn_kernel)
  const float* ln1_w = (const float*)d_in[2];
  const float* ln1_b = (const float*)d_in[3];
  const float* w_qkv = (const float*)d_in[4];
  const float* w_out = (const float*)d_in[5];
  const float* b_out = (const float*)d_in[6];
  const float* ln2_w = (const float*)d_in[7];
  const float* ln2_b = (const float*)d_in[8];
  const float* w1    = (const float*)d_in[9];
  const float* b1    = (const float*)d_in[10];
  const float* w2    = (const float*)d_in[11];
  const float* b2    = (const float*)d_in[12];

  char* ws = (char*)d_ws;
  size_t off = 0;
  auto alloc = [&](size_t bytes) { char* p = ws + off; off += (bytes + 255) & ~(size_t)255; return p; };
  short* wqkvT = (short*)alloc((size_t)L * 1536 * 512 * 2);
  short* woutT = (short*)alloc((size_t)L * 512 * 512 * 2);
  short* w1T   = (short*)alloc((size_t)L * 512 * 2048 * 2);
  short* w2T   = (short*)alloc((size_t)L * 2048 * 512 * 2);
  short* hln   = (short*)alloc((size_t)M_ROWS * 512 * 2);
  short* big   = (short*)alloc((size_t)M_ROWS * 2048 * 2);  // qkv (1536 cols) & ff (2048 cols) share
  short* oatt  = (short*)alloc((size_t)M_ROWS * 512 * 2);
  short* Vtg   = (short*)alloc((size_t)BATCH * H * 64 * VTP * 2);
  short* qkv = big;
  short* ff  = big;

  float* x = (float*)d_out;   // fp32 residual stream lives in d_out
  // No upfront copy: layer 0 reads x_in directly (ln1 + out-proj residual);
  // out-proj MODE 2 writes ALL of x before anything reads it.

  transpose_all_kernel<<<12288, 256, 0, stream>>>(w_qkv, wqkvT, w_out, woutT, w1, w1T, w2, w2T);

  for (int l = 0; l < L; ++l) {
    const float* xl = (l == 0) ? x_in : x;   // residual state entering this layer
    // --- attention block ---
    ln_kernel<<<M_ROWS / 4, 256, 0, stream>>>(xl, ln1_w + l * 512, ln1_b + l * 512, hln);
    gemm256_kernel<3, 8><<<dim3((1536 / 256) * (M_ROWS / 256)), 512, 0, stream>>>(
        hln, wqkvT + (size_t)l * 1536 * 512, nullptr, qkv, Vtg, M_ROWS, 1536);
    attn_kernel<<<dim3(1024), 256, 0, stream>>>(qkv, Vtg, oatt);
    gemm128_kernel<2, 64><<<dim3((512 / 64) * (M_ROWS / 128)), 256, 0, stream>>>(
        oatt, woutT + (size_t)l * 512 * 512, b_out + l * 512, xl, x, M_ROWS, 512, 512);
    // --- MLP block ---
    ln_kernel<<<M_ROWS / 4, 256, 0, stream>>>(x, ln2_w + l * 512, ln2_b + l * 512, hln);
    gemm256_kernel<1, 8><<<dim3((2048 / 256) * (M_ROWS / 256)), 512, 0, stream>>>(
        hln, w1T + (size_t)l * 512 * 2048, b1 + l * 2048, ff, nullptr, M_ROWS, 2048);
    gemm128_kernel<2, 64><<<dim3((512 / 64) * (M_ROWS / 128)), 256, 0, stream>>>(
        ff, w2T + (size_t)l * 2048 * 512, b2 + l * 512, x, x, M_ROWS, 512, 2048);
  }
}